// Round 8
// baseline (5556.184 us; speedup 1.0000x reference)
//
#include <hip/hip_runtime.h>
#include <stdint.h>

#define H   512
#define B   64
#define T   512
#define E   256
#define G3  1536   // 3*H
#define CT  64     // time-chunk length (T/CT = 8 chunks)
#define NBG 4      // independent batch groups (16 batches each)
#define NUG 16     // unit blocks per direction (32 units each)

typedef short s16;
typedef unsigned short u16;
typedef unsigned int u32;
typedef __attribute__((ext_vector_type(8))) short   short8;
typedef __attribute__((ext_vector_type(4))) float   f32x4;
typedef __attribute__((ext_vector_type(4))) unsigned int u32x4;
typedef __bf16 bf8_t __attribute__((ext_vector_type(8)));

__device__ __forceinline__ u16 f2b(float f) {
    union { float f; unsigned int i; } v; v.f = f;
    unsigned int r = v.i + 0x7FFF + ((v.i >> 16) & 1);
    return (u16)(r >> 16);
}
__device__ __forceinline__ float sigm(float x)  { return 1.f / (1.f + __expf(-x)); }
__device__ __forceinline__ float tanhs(float x) { return 1.f - 2.f / (1.f + __expf(2.f * x)); }

// ------------------------------------------------------- fp32 -> bf16 weight convert
__global__ void k_cvt(const float* __restrict__ src, u16* __restrict__ dst, int n) {
    int i = blockIdx.x * 256 + threadIdx.x;
    int stride = gridDim.x * 256;
    for (; i < n; i += stride) dst[i] = f2b(src[i]);
}

// ------------------------------------------------------- init h32/hbf/flags
__global__ void k_init(float* __restrict__ h32, u16* __restrict__ hbf, int* __restrict__ bar) {
    int i = blockIdx.x * 256 + threadIdx.x;      // 131072 = 2 dirs * 2 slices * B*H
    hbf[i] = 0;
    if (i < 65536) h32[i] = 0.f;                 // 2 dirs * B*H carry
    if (i < 4096)  bar[i] = 0;                   // flags (16-int / 64B stride each)
}

// ------------------------------------------------------- xg chunk GEMM (MFMA)
// Writes xgT[d][tl][n][b] (fp32) = A[b,t,:K] . Wbf[d][n][:K] + bih[d][n]
// m-mapping: b = m&63, tl = m>>6 (t = t0(d,c)+tl). MFMA operands are SWAPPED
// (first = B-rows) so D-cols carry m: the 16 store lanes (r16 -> b) write 16
// consecutive floats -> coalesced C stores in the chunk-friendly [tl][n][b]
// layout (chunk reads f32x4 along b).
#define BM 128
#define BN 128
#define BK 32

__global__ __launch_bounds__(256)
void k_gemm_xg(const int* __restrict__ sent, const void* __restrict__ Abuf, int aIsF32,
               const u16* __restrict__ Wbf, const float* __restrict__ bih,
               float* __restrict__ xgT, int K, int c) {
    int d  = blockIdx.z;
    int t0 = d ? (T - (c + 1) * CT) : c * CT;
    const u16* Bw = Wbf + (long)d * G3 * K;
    const float* bias = bih + (long)d * G3;
    float* C = xgT + (long)d * (long)CT * G3 * B;

    __shared__ __align__(16) s16 lA[BM * BK];
    __shared__ __align__(16) s16 lB[BN * BK];

    int tid  = threadIdx.x;
    int lane = tid & 63;
    int wv   = tid >> 6;
    int wm   = wv >> 1, wn = wv & 1;
    int q    = lane >> 4, r16 = lane & 15;

    long m0 = (long)blockIdx.x * BM;
    long n0 = (long)blockIdx.y * BN;

    const float* rowAf[2];
    const s16*   rowAh[2];
    const u16*   rowB[2];
    #pragma unroll
    for (int i = 0; i < 2; i++) {
        int ch = tid + i * 256;
        int r  = ch >> 2, cc = (ch & 3) * 8;
        long m = m0 + r;
        int  bb_ = (int)(m & 63), tl = (int)(m >> 6);   // m = (tl<<6)|b
        int  t  = t0 + tl;
        if (aIsF32) rowAf[i] = (const float*)Abuf + (long)sent[bb_ * T + t] * K + cc;
        else        rowAh[i] = (const s16*)Abuf + ((long)bb_ * T + t) * K + cc;
        rowB[i] = Bw + (n0 + r) * K + cc;
    }

    f32x4 acc[4][4];
    #pragma unroll
    for (int i = 0; i < 4; i++)
        #pragma unroll
        for (int j = 0; j < 4; j++) acc[i][j] = (f32x4){0.f, 0.f, 0.f, 0.f};

    for (long k0 = 0; k0 < K; k0 += BK) {
        #pragma unroll
        for (int i = 0; i < 2; i++) {
            if (aIsF32) {
                float4 v0 = *(const float4*)(rowAf[i] + k0);
                float4 v1 = *(const float4*)(rowAf[i] + k0 + 4);
                short8 pk;
                pk[0] = (s16)f2b(v0.x); pk[1] = (s16)f2b(v0.y);
                pk[2] = (s16)f2b(v0.z); pk[3] = (s16)f2b(v0.w);
                pk[4] = (s16)f2b(v1.x); pk[5] = (s16)f2b(v1.y);
                pk[6] = (s16)f2b(v1.z); pk[7] = (s16)f2b(v1.w);
                ((short8*)lA)[tid + i * 256] = pk;
            } else {
                ((short8*)lA)[tid + i * 256] = *(const short8*)(rowAh[i] + k0);
            }
            ((short8*)lB)[tid + i * 256] = *(const short8*)((const s16*)rowB[i] + k0);
        }
        __syncthreads();

        bf8_t af[4], bf[4];
        #pragma unroll
        for (int mt = 0; mt < 4; mt++)
            af[mt] = ((const bf8_t*)lA)[(wm * 64 + mt * 16 + r16) * 4 + q];
        #pragma unroll
        for (int nt = 0; nt < 4; nt++)
            bf[nt] = ((const bf8_t*)lB)[(wn * 64 + nt * 16 + r16) * 4 + q];
        #pragma unroll
        for (int mt = 0; mt < 4; mt++)
            #pragma unroll
            for (int nt = 0; nt < 4; nt++)
                acc[mt][nt] = __builtin_amdgcn_mfma_f32_16x16x32_bf16(
                                  bf[nt], af[mt], acc[mt][nt], 0, 0, 0);   // swapped
        __syncthreads();
    }

    // D layout (swapped): row (q*4+rg) -> n-sub, col (r16) -> m-sub
    #pragma unroll
    for (int nt = 0; nt < 4; nt++) {
        f32x4 bv = *(const f32x4*)(bias + n0 + wn * 64 + nt * 16 + q * 4);
        #pragma unroll
        for (int mt = 0; mt < 4; mt++) {
            long m = m0 + wm * 64 + mt * 16 + r16;
            long tl = m >> 6, b = m & 63;
            #pragma unroll
            for (int rg = 0; rg < 4; rg++) {
                long n = n0 + wn * 64 + nt * 16 + q * 4 + rg;
                C[(tl * G3 + n) * B + b] = acc[mt][nt][rg] + bv[rg];
            }
        }
    }
}

// ------------------------------------------------------- wave-autonomous chunk recurrence
// Grid (NUG=16, NBG=4, 2 dirs) x 64 thr: 128 single-wave blocks, all co-resident.
// Each block owns 32 units (2 n-tiles per gate); weights in 96 KB LDS (R3-proven
// staging). Sync = R1/R7-proven protocol verbatim: write-through (sc0 sc1) h
// stores + vmcnt drain -> per-wave flag store (own 64B line, no RMW) -> wave-wide
// flag poll -> one monolithic cache-bypass bulk load (internal waitcnt).
// Halving the block count halves the aggregate bypass bulk traffic (4->2 MB/step),
// the measured dominant step cost.
__global__ __launch_bounds__(64, 1)
void k_chunk(const u16* __restrict__ Whhbf, const float* __restrict__ bhh,
             const float* __restrict__ xgT, float* __restrict__ h32,
             u16* __restrict__ hbf, int c, u16* __restrict__ x1out, int writeX1,
             int* __restrict__ flags) {
    int ug = blockIdx.x;                 // unit group: units ug*32..+31
    int bg = blockIdx.y;                 // batch group: batches bg*16..+15
    int d  = blockIdx.z;
    int lane = threadIdx.x;              // 0..63
    int q = lane >> 4, cc = lane & 15;
    int u0 = ug * 32;
    int u  = u0 + cc;                    // n-tile 0 unit; tile 1 = u + 16

    const u16* W    = Whhbf + (long)d * G3 * H;
    const float* bb = bhh + (long)d * G3;
    const float* xgf = xgT + (long)d * (long)CT * G3 * B;
    float* h32d = h32 + (long)d * B * H;
    u16*   hbfd = hbf + (long)d * 2 * B * H;
    int*   fgrp   = flags + (d * NBG + bg) * NUG * 16;   // this domain's 16 flags
    int*   myflag = fgrp + ug * 16;
    const int* fpoll = fgrp + (lane & 15) * 16;

    // ---- stage this block's weights into LDS: [gate][kc][nt][lane] 16B frags ----
    // B-frag: lane holds W[col = u0+nt*16+cc][k = kc*32 + q*8 ..+7].
    __shared__ __align__(16) u16 lw[6144 * 8];   // 98304 B
    for (int r = 0; r < 96; r++) {
        int f    = r * 64 + lane;
        int nt   = r & 1;
        int kcg  = r >> 1;              // gate*16 + kc
        int kc   = kcg & 15;
        int gate = kcg >> 4;
        int row  = u0 + nt * 16 + cc;
        int k    = kc * 32 + q * 8;
        *(short8*)(lw + (long)f * 8) =
            *(const short8*)(W + (long)(gate * H + row) * H + k);
    }
    const bf8_t* lwf = (const bf8_t*)lw;   // index: ((gate*16+kc)*2+nt)*64 + lane

    float br0 = bb[u],          bz0 = bb[H + u],      bn0 = bb[2 * H + u];
    float br1 = bb[u + 16],     bz1 = bb[H + u + 16], bn1 = bb[2 * H + u + 16];

    // fp32 h-carry: lane holds h[b = bg*16 + q*4 + rg][u] and [u+16]
    float hp0[4], hp1[4];
    #pragma unroll
    for (int rg = 0; rg < 4; rg++) {
        hp0[rg] = h32d[(long)(bg * 16 + q * 4 + rg) * H + u];
        hp1[rg] = h32d[(long)(bg * 16 + q * 4 + rg) * H + u + 16];
    }

    int base = c * CT;
    int bA = bg * 16 + cc;               // A-frag row (m = lane&15) = batch

    for (int sl = 0; sl < CT; sl++) {
        int s    = base + sl;
        int tl   = d ? (CT - 1 - sl) : sl;
        int time = d ? (T - 1 - s) : s;

        // xg loads ([tl][n][b]: f32x4 along b; overlap the hbf fetch latency)
        long xb = ((long)tl * G3 + u) * B + (bg * 16 + q * 4);
        f32x4 xr0 = *(const f32x4*)(xgf + xb);
        f32x4 xz0 = *(const f32x4*)(xgf + xb + (long)H * B);
        f32x4 xn0 = *(const f32x4*)(xgf + xb + (long)2 * H * B);
        f32x4 xr1 = *(const f32x4*)(xgf + xb + 16L * B);
        f32x4 xz1 = *(const f32x4*)(xgf + xb + (long)H * B + 16L * B);
        f32x4 xn1 = *(const f32x4*)(xgf + xb + (long)2 * H * B + 16L * B);

        // A-fragments: one monolithic bypass-load block (internal waitcnt).
        // 16 KB/wave: h[16 batches of this bg][all 512 units].
        const u16* hq = hbfd + (long)(s & 1) * B * H + (long)bA * H + q * 8;
        u32x4 a0,a1,a2,a3,a4,a5,a6,a7,a8,a9,a10,a11,a12,a13,a14,a15;
        asm volatile(
            "global_load_dwordx4 %0,  %16, off sc0 sc1\n\t"
            "global_load_dwordx4 %1,  %16, off offset:64  sc0 sc1\n\t"
            "global_load_dwordx4 %2,  %16, off offset:128 sc0 sc1\n\t"
            "global_load_dwordx4 %3,  %16, off offset:192 sc0 sc1\n\t"
            "global_load_dwordx4 %4,  %16, off offset:256 sc0 sc1\n\t"
            "global_load_dwordx4 %5,  %16, off offset:320 sc0 sc1\n\t"
            "global_load_dwordx4 %6,  %16, off offset:384 sc0 sc1\n\t"
            "global_load_dwordx4 %7,  %16, off offset:448 sc0 sc1\n\t"
            "global_load_dwordx4 %8,  %16, off offset:512 sc0 sc1\n\t"
            "global_load_dwordx4 %9,  %16, off offset:576 sc0 sc1\n\t"
            "global_load_dwordx4 %10, %16, off offset:640 sc0 sc1\n\t"
            "global_load_dwordx4 %11, %16, off offset:704 sc0 sc1\n\t"
            "global_load_dwordx4 %12, %16, off offset:768 sc0 sc1\n\t"
            "global_load_dwordx4 %13, %16, off offset:832 sc0 sc1\n\t"
            "global_load_dwordx4 %14, %16, off offset:896 sc0 sc1\n\t"
            "global_load_dwordx4 %15, %16, off offset:960 sc0 sc1\n\t"
            "s_waitcnt vmcnt(0)"
            : "=&v"(a0),"=&v"(a1),"=&v"(a2),"=&v"(a3),
              "=&v"(a4),"=&v"(a5),"=&v"(a6),"=&v"(a7),
              "=&v"(a8),"=&v"(a9),"=&v"(a10),"=&v"(a11),
              "=&v"(a12),"=&v"(a13),"=&v"(a14),"=&v"(a15)
            : "v"(hq)
            : "memory");
        bf8_t af[16];
        af[0]=__builtin_bit_cast(bf8_t,a0);   af[1]=__builtin_bit_cast(bf8_t,a1);
        af[2]=__builtin_bit_cast(bf8_t,a2);   af[3]=__builtin_bit_cast(bf8_t,a3);
        af[4]=__builtin_bit_cast(bf8_t,a4);   af[5]=__builtin_bit_cast(bf8_t,a5);
        af[6]=__builtin_bit_cast(bf8_t,a6);   af[7]=__builtin_bit_cast(bf8_t,a7);
        af[8]=__builtin_bit_cast(bf8_t,a8);   af[9]=__builtin_bit_cast(bf8_t,a9);
        af[10]=__builtin_bit_cast(bf8_t,a10); af[11]=__builtin_bit_cast(bf8_t,a11);
        af[12]=__builtin_bit_cast(bf8_t,a12); af[13]=__builtin_bit_cast(bf8_t,a13);
        af[14]=__builtin_bit_cast(bf8_t,a14); af[15]=__builtin_bit_cast(bf8_t,a15);

        f32x4 aR0 = (f32x4){0.f,0.f,0.f,0.f}, aR1 = (f32x4){0.f,0.f,0.f,0.f};
        f32x4 aZ0 = (f32x4){0.f,0.f,0.f,0.f}, aZ1 = (f32x4){0.f,0.f,0.f,0.f};
        f32x4 aN0 = (f32x4){0.f,0.f,0.f,0.f}, aN1 = (f32x4){0.f,0.f,0.f,0.f};
        #pragma unroll
        for (int kc = 0; kc < 16; kc++) {
            aR0 = __builtin_amdgcn_mfma_f32_16x16x32_bf16(af[kc], lwf[((0*16+kc)*2+0)*64 + lane], aR0, 0, 0, 0);
            aR1 = __builtin_amdgcn_mfma_f32_16x16x32_bf16(af[kc], lwf[((0*16+kc)*2+1)*64 + lane], aR1, 0, 0, 0);
            aZ0 = __builtin_amdgcn_mfma_f32_16x16x32_bf16(af[kc], lwf[((1*16+kc)*2+0)*64 + lane], aZ0, 0, 0, 0);
            aZ1 = __builtin_amdgcn_mfma_f32_16x16x32_bf16(af[kc], lwf[((1*16+kc)*2+1)*64 + lane], aZ1, 0, 0, 0);
            aN0 = __builtin_amdgcn_mfma_f32_16x16x32_bf16(af[kc], lwf[((2*16+kc)*2+0)*64 + lane], aN0, 0, 0, 0);
            aN1 = __builtin_amdgcn_mfma_f32_16x16x32_bf16(af[kc], lwf[((2*16+kc)*2+1)*64 + lane], aN1, 0, 0, 0);
        }

        u16* hnb = hbfd + (long)((s + 1) & 1) * B * H;
        #pragma unroll
        for (int rg = 0; rg < 4; rg++) {
            int b = bg * 16 + q * 4 + rg;         // D layout: row = (lane>>4)*4+reg
            // n-tile 0: unit u
            float r = sigm(xr0[rg] + aR0[rg] + br0);
            float z = sigm(xz0[rg] + aZ0[rg] + bz0);
            float n = tanhs(xn0[rg] + r * (aN0[rg] + bn0));
            float hh = (1.f - z) * n + z * hp0[rg];
            hp0[rg] = hh;
            u16 hv = f2b(hh);
            asm volatile("global_store_short %0, %1, off sc0 sc1"
                         :: "v"(hnb + (long)b * H + u), "v"((unsigned int)hv) : "memory");
            // n-tile 1: unit u+16
            float r1 = sigm(xr1[rg] + aR1[rg] + br1);
            float z1 = sigm(xz1[rg] + aZ1[rg] + bz1);
            float n1 = tanhs(xn1[rg] + r1 * (aN1[rg] + bn1));
            float hh1 = (1.f - z1) * n1 + z1 * hp1[rg];
            hp1[rg] = hh1;
            u16 hv1 = f2b(hh1);
            asm volatile("global_store_short %0, %1, off sc0 sc1"
                         :: "v"(hnb + (long)b * H + u + 16), "v"((unsigned int)hv1) : "memory");
            if (writeX1) {
                x1out[((long)b * T + time) * 1024 + d * H + u]      = hv;
                x1out[((long)b * T + time) * 1024 + d * H + u + 16] = hv1;
            }
        }

        // drain this wave's stores (WT ack => device-visible), then flag + poll.
        asm volatile("s_waitcnt vmcnt(0)" ::: "memory");
        if (sl < CT - 1) {
            int tgt = s + 1;
            if (lane == 0)
                asm volatile("global_store_dword %0, %1, off sc0 sc1"
                             :: "v"(myflag), "v"(tgt) : "memory");
            int v;
            do {
                asm volatile("global_load_dword %0, %1, off sc0 sc1\n\t"
                             "s_waitcnt vmcnt(0)"
                             : "=v"(v) : "v"(fpoll) : "memory");
            } while (!__all(v >= tgt));
        }
        // last step: no flag/poll — next dispatch is stream-ordered (kernel boundary).
    }

    // spill fp32 carry for next chunk dispatch / k_fc (kernel-boundary coherence)
    #pragma unroll
    for (int rg = 0; rg < 4; rg++) {
        h32d[(long)(bg * 16 + q * 4 + rg) * H + u]      = hp0[rg];
        h32d[(long)(bg * 16 + q * 4 + rg) * H + u + 16] = hp1[rg];
    }
}

// ------------------------------------------------------- final FC (fp32)
__global__ __launch_bounds__(256)
void k_fc(const float* __restrict__ h32, const float* __restrict__ fcw,
          const float* __restrict__ fcb, float* __restrict__ out) {
    int b   = blockIdx.x;
    int tid = threadIdx.x;
    float p[10];
    #pragma unroll
    for (int o = 0; o < 10; o++) p[o] = 0.f;
    for (int k = tid; k < 1024; k += 256) {
        int dd = k >> 9, kk = k & 511;
        float hv = h32[(long)dd * B * H + (long)b * H + kk];
        #pragma unroll
        for (int o = 0; o < 10; o++) p[o] += hv * fcw[o * 1024 + k];
    }
    __shared__ float red[10][256];
    #pragma unroll
    for (int o = 0; o < 10; o++) red[o][tid] = p[o];
    __syncthreads();
    for (int off = 128; off > 0; off >>= 1) {
        if (tid < off)
            #pragma unroll
            for (int o = 0; o < 10; o++) red[o][tid] += red[o][tid + off];
        __syncthreads();
    }
    if (tid < 10) out[b * 10 + tid] = red[tid][0] + fcb[tid];
}

// ------------------------------------------------------- launcher
extern "C" void kernel_launch(void* const* d_in, const int* in_sizes, int n_in,
                              void* d_out, int out_size, void* d_ws, size_t ws_size,
                              hipStream_t stream) {
    const int*   sent = (const int*)d_in[0];
    const float* emb  = (const float*)d_in[1];
    const float* wih0 = (const float*)d_in[2];
    const float* whh0 = (const float*)d_in[3];
    const float* bih0 = (const float*)d_in[4];
    const float* bhh0 = (const float*)d_in[5];
    const float* wih1 = (const float*)d_in[6];
    const float* whh1 = (const float*)d_in[7];
    const float* bih1 = (const float*)d_in[8];
    const float* bhh1 = (const float*)d_in[9];
    const float* fcw  = (const float*)d_in[10];
    const float* fcb  = (const float*)d_in[11];
    float* outp = (float*)d_out;

    // workspace layout — ~132.2 MB (proven-safe envelope: >=134.5 MB)
    char*  ws  = (char*)d_ws;
    float* xg  = (float*)(ws);                           // 2*CT*G3*B*4 = 50,331,648 B
    u16*   x1  = (u16*)(ws + 50331648L);                 // B*T*1024*2  = 67,108,864 B
    float* h32 = (float*)(ws + 50331648L + 67108864L);   // 2*B*H*4     =    262,144 B
    u16*   hbf = (u16*)(ws + 50331648L + 67108864L + 262144L);   // 262,144 B
    int*   bar = (int*)(ws + 50331648L + 67108864L + 262144L + 262144L); // 16,384 B flags
    u16*   wbf = (u16*)(ws + 50331648L + 67108864L + 262144L + 262144L + 16384L);
    u16* wih0b = wbf;                      // 2*1536*256  =   786,432 el
    u16* wih1b = wbf + 786432L;            // 2*1536*1024 = 3,145,728 el
    u16* whh0b = wbf + 786432L + 3145728L; // 2*1536*512  = 1,572,864 el
    u16* whh1b = whh0b + 1572864L;         // 1,572,864 el

    // convert weights fp32 -> bf16 (graph-safe, runs every launch)
    k_cvt<<<512, 256, 0, stream>>>(wih0, wih0b, 786432);
    k_cvt<<<512, 256, 0, stream>>>(wih1, wih1b, 3145728);
    k_cvt<<<512, 256, 0, stream>>>(whh0, whh0b, 1572864);
    k_cvt<<<512, 256, 0, stream>>>(whh1, whh1b, 1572864);

    dim3 gg(32, 12, 2);      // GEMM: 32 m-blocks x 12 n-tiles x 2 dirs
    dim3 gc(NUG, NBG, 2);    // recurrence: 16 unit-blocks x 4 batch-groups x 2 dirs

    // ---- layer 0 (embedding gather fused into GEMM A-staging) ----
    k_init<<<512, 256, 0, stream>>>(h32, hbf, bar);
    for (int c = 0; c < T / CT; c++) {
        k_gemm_xg<<<gg, 256, 0, stream>>>(sent, emb, 1, wih0b, bih0, xg, E, c);
        k_chunk<<<gc, 64, 0, stream>>>(whh0b, bhh0, xg, h32, hbf, c, x1, 1, bar);
    }

    // ---- layer 1 (A = x1, already bf16) ----
    k_init<<<512, 256, 0, stream>>>(h32, hbf, bar);
    for (int c = 0; c < T / CT; c++) {
        k_gemm_xg<<<gg, 256, 0, stream>>>(sent, x1, 0, wih1b, bih1, xg, 2 * H, c);
        k_chunk<<<gc, 64, 0, stream>>>(whh1b, bhh1, xg, h32, hbf, c, (u16*)nullptr, 0, bar);
    }

    k_fc<<<B, 256, 0, stream>>>(h32, fcw, fcb, outp);
}

// Round 9
// 3792.286 us; speedup vs baseline: 1.4651x; 1.4651x over previous
//
#include <hip/hip_runtime.h>
#include <stdint.h>

#define H   512
#define B   64
#define T   512
#define E   256
#define G3  1536   // 3*H
#define CT  64     // time-chunk length (T/CT = 8 chunks)
#define NBG 4      // independent batch groups (16 batches each)
#define NUG 32     // unit blocks per direction (16 units each)

typedef short s16;
typedef unsigned short u16;
typedef unsigned int u32;
typedef __attribute__((ext_vector_type(8))) short   short8;
typedef __attribute__((ext_vector_type(4))) float   f32x4;
typedef __attribute__((ext_vector_type(4))) unsigned int u32x4;
typedef __bf16 bf8_t __attribute__((ext_vector_type(8)));

__device__ __forceinline__ u16 f2b(float f) {
    union { float f; unsigned int i; } v; v.f = f;
    unsigned int r = v.i + 0x7FFF + ((v.i >> 16) & 1);
    return (u16)(r >> 16);
}
__device__ __forceinline__ float sigm(float x)  { return 1.f / (1.f + __expf(-x)); }
__device__ __forceinline__ float tanhs(float x) { return 1.f - 2.f / (1.f + __expf(2.f * x)); }

// ------------------------------------------------------- fp32 -> bf16 weight convert
__global__ void k_cvt(const float* __restrict__ src, u16* __restrict__ dst, int n) {
    int i = blockIdx.x * 256 + threadIdx.x;
    int stride = gridDim.x * 256;
    for (; i < n; i += stride) dst[i] = f2b(src[i]);
}

// ------------------------------------------------------- init h32/hbf/flags
__global__ void k_init(float* __restrict__ h32, u16* __restrict__ hbf, int* __restrict__ bar) {
    int i = blockIdx.x * 256 + threadIdx.x;      // 131072 = 2 dirs * 2 slices * B*H
    hbf[i] = 0;
    if (i < 65536) h32[i] = 0.f;                 // 2 dirs * B*H carry
    if (i < 4096)  bar[i] = 0;                   // 2*4*32 flags, 16-int (64B) stride
}

// ------------------------------------------------------- xg chunk GEMM (MFMA)
// Writes xgT[d][tl][n][b] (fp32) = A[b,t,:K] . Wbf[d][n][:K] + bih[d][n]
// m-mapping: b = m&63, tl = m>>6 (t = t0(d,c)+tl). MFMA operands are SWAPPED
// (first = B-rows) so D-cols carry m: the 16 store lanes (r16 -> b) write 16
// consecutive floats -> coalesced C stores in the chunk-friendly [tl][n][b]
// layout (chunk reads f32x4 along b).
#define BM 128
#define BN 128
#define BK 32

__global__ __launch_bounds__(256)
void k_gemm_xg(const int* __restrict__ sent, const void* __restrict__ Abuf, int aIsF32,
               const u16* __restrict__ Wbf, const float* __restrict__ bih,
               float* __restrict__ xgT, int K, int c) {
    int d  = blockIdx.z;
    int t0 = d ? (T - (c + 1) * CT) : c * CT;
    const u16* Bw = Wbf + (long)d * G3 * K;
    const float* bias = bih + (long)d * G3;
    float* C = xgT + (long)d * (long)CT * G3 * B;

    __shared__ __align__(16) s16 lA[BM * BK];
    __shared__ __align__(16) s16 lB[BN * BK];

    int tid  = threadIdx.x;
    int lane = tid & 63;
    int wv   = tid >> 6;
    int wm   = wv >> 1, wn = wv & 1;
    int q    = lane >> 4, r16 = lane & 15;

    long m0 = (long)blockIdx.x * BM;
    long n0 = (long)blockIdx.y * BN;

    const float* rowAf[2];
    const s16*   rowAh[2];
    const u16*   rowB[2];
    #pragma unroll
    for (int i = 0; i < 2; i++) {
        int ch = tid + i * 256;
        int r  = ch >> 2, cc = (ch & 3) * 8;
        long m = m0 + r;
        int  bb_ = (int)(m & 63), tl = (int)(m >> 6);   // m = (tl<<6)|b
        int  t  = t0 + tl;
        if (aIsF32) rowAf[i] = (const float*)Abuf + (long)sent[bb_ * T + t] * K + cc;
        else        rowAh[i] = (const s16*)Abuf + ((long)bb_ * T + t) * K + cc;
        rowB[i] = Bw + (n0 + r) * K + cc;
    }

    f32x4 acc[4][4];
    #pragma unroll
    for (int i = 0; i < 4; i++)
        #pragma unroll
        for (int j = 0; j < 4; j++) acc[i][j] = (f32x4){0.f, 0.f, 0.f, 0.f};

    for (long k0 = 0; k0 < K; k0 += BK) {
        #pragma unroll
        for (int i = 0; i < 2; i++) {
            if (aIsF32) {
                float4 v0 = *(const float4*)(rowAf[i] + k0);
                float4 v1 = *(const float4*)(rowAf[i] + k0 + 4);
                short8 pk;
                pk[0] = (s16)f2b(v0.x); pk[1] = (s16)f2b(v0.y);
                pk[2] = (s16)f2b(v0.z); pk[3] = (s16)f2b(v0.w);
                pk[4] = (s16)f2b(v1.x); pk[5] = (s16)f2b(v1.y);
                pk[6] = (s16)f2b(v1.z); pk[7] = (s16)f2b(v1.w);
                ((short8*)lA)[tid + i * 256] = pk;
            } else {
                ((short8*)lA)[tid + i * 256] = *(const short8*)(rowAh[i] + k0);
            }
            ((short8*)lB)[tid + i * 256] = *(const short8*)((const s16*)rowB[i] + k0);
        }
        __syncthreads();

        bf8_t af[4], bf[4];
        #pragma unroll
        for (int mt = 0; mt < 4; mt++)
            af[mt] = ((const bf8_t*)lA)[(wm * 64 + mt * 16 + r16) * 4 + q];
        #pragma unroll
        for (int nt = 0; nt < 4; nt++)
            bf[nt] = ((const bf8_t*)lB)[(wn * 64 + nt * 16 + r16) * 4 + q];
        #pragma unroll
        for (int mt = 0; mt < 4; mt++)
            #pragma unroll
            for (int nt = 0; nt < 4; nt++)
                acc[mt][nt] = __builtin_amdgcn_mfma_f32_16x16x32_bf16(
                                  bf[nt], af[mt], acc[mt][nt], 0, 0, 0);   // swapped
        __syncthreads();
    }

    // D layout (swapped): row (q*4+rg) -> n-sub, col (r16) -> m-sub
    #pragma unroll
    for (int nt = 0; nt < 4; nt++) {
        f32x4 bv = *(const f32x4*)(bias + n0 + wn * 64 + nt * 16 + q * 4);
        #pragma unroll
        for (int mt = 0; mt < 4; mt++) {
            long m = m0 + wm * 64 + mt * 16 + r16;
            long tl = m >> 6, b = m & 63;
            #pragma unroll
            for (int rg = 0; rg < 4; rg++) {
                long n = n0 + wn * 64 + nt * 16 + q * 4 + rg;
                C[(tl * G3 + n) * B + b] = acc[mt][nt][rg] + bv[rg];
            }
        }
    }
}

// ------------------------------------------------------- wave-autonomous chunk recurrence
// Grid (NUG=32, NBG=4, 2 dirs) x 64 thr: 256 single-wave blocks, all co-resident.
// R1's fastest-measured chunk (3.38 us/step) verbatim: weights as a register-
// declared w[3][16] array (compiler remats to cached global loads that pipeline
// under MFMA issue — measured FASTER than LDS ds_read on the issue path, R7/R8).
// Cross-block h state (hbf) via write-through (sc0 sc1) stores + one monolithic
// cache-bypass load block (internal waitcnt, early-clobber outputs). Sync =
// distributed per-wave flag stores (own 64B line, no RMW) + wave-wide poll.
__global__ __launch_bounds__(64, 1)
void k_chunk(const u16* __restrict__ Whhbf, const float* __restrict__ bhh,
             const float* __restrict__ xgT, float* __restrict__ h32,
             u16* __restrict__ hbf, int c, u16* __restrict__ x1out, int writeX1,
             int* __restrict__ flags) {
    int ug = blockIdx.x;                 // unit group: units ug*16..+15
    int bg = blockIdx.y;                 // batch group: batches bg*16..+15
    int d  = blockIdx.z;
    int lane = threadIdx.x;              // 0..63
    int q = lane >> 4, cc = lane & 15;
    int u0 = ug * 16;
    int u  = u0 + cc;

    const u16* W    = Whhbf + (long)d * G3 * H;
    const float* bb = bhh + (long)d * G3;
    const float* xgf = xgT + (long)d * (long)CT * G3 * B;
    float* h32d = h32 + (long)d * B * H;
    u16*   hbfd = hbf + (long)d * 2 * B * H;
    int*   fgrp   = flags + (d * NBG + bg) * NUG * 16;   // this domain's 32 flags
    int*   myflag = fgrp + ug * 16;
    const int* fpoll = fgrp + (lane & 31) * 16;

    // ---- weight slice as registers (compiler remats to cached loads) ----
    // B-frag layout: lane holds B[col=lane&15][k = (lane>>4)*8 .. +7] of the K=32 tile.
    bf8_t w[3][16];
    #pragma unroll
    for (int gate = 0; gate < 3; gate++)
        #pragma unroll
        for (int kc = 0; kc < 16; kc++)
            w[gate][kc] = *(const bf8_t*)(W + (long)(gate * H + u0 + cc) * H + kc * 32 + q * 8);

    float br = bb[u], bz = bb[H + u], bn = bb[2 * H + u];

    // fp32 h-carry: lane holds h[b = bg*16 + q*4 + rg][u]
    float hp[4];
    #pragma unroll
    for (int rg = 0; rg < 4; rg++)
        hp[rg] = h32d[(long)(bg * 16 + q * 4 + rg) * H + u];

    int base = c * CT;
    int bA = bg * 16 + cc;               // A-frag row (m = lane&15) = batch

    for (int sl = 0; sl < CT; sl++) {
        int s    = base + sl;
        int tl   = d ? (CT - 1 - sl) : sl;
        int time = d ? (T - 1 - s) : s;

        // xg loads ([tl][n][b]: f32x4 along b; overlap the hbf fetch latency)
        long xb = ((long)tl * G3 + u) * B + (bg * 16 + q * 4);
        f32x4 xrv = *(const f32x4*)(xgf + xb);
        f32x4 xzv = *(const f32x4*)(xgf + xb + (long)H * B);
        f32x4 xnv = *(const f32x4*)(xgf + xb + (long)2 * H * B);

        // A-fragments: one monolithic bypass-load block (internal waitcnt).
        const u16* hq = hbfd + (long)(s & 1) * B * H + (long)bA * H + q * 8;
        u32x4 a0,a1,a2,a3,a4,a5,a6,a7,a8,a9,a10,a11,a12,a13,a14,a15;
        asm volatile(
            "global_load_dwordx4 %0,  %16, off sc0 sc1\n\t"
            "global_load_dwordx4 %1,  %16, off offset:64  sc0 sc1\n\t"
            "global_load_dwordx4 %2,  %16, off offset:128 sc0 sc1\n\t"
            "global_load_dwordx4 %3,  %16, off offset:192 sc0 sc1\n\t"
            "global_load_dwordx4 %4,  %16, off offset:256 sc0 sc1\n\t"
            "global_load_dwordx4 %5,  %16, off offset:320 sc0 sc1\n\t"
            "global_load_dwordx4 %6,  %16, off offset:384 sc0 sc1\n\t"
            "global_load_dwordx4 %7,  %16, off offset:448 sc0 sc1\n\t"
            "global_load_dwordx4 %8,  %16, off offset:512 sc0 sc1\n\t"
            "global_load_dwordx4 %9,  %16, off offset:576 sc0 sc1\n\t"
            "global_load_dwordx4 %10, %16, off offset:640 sc0 sc1\n\t"
            "global_load_dwordx4 %11, %16, off offset:704 sc0 sc1\n\t"
            "global_load_dwordx4 %12, %16, off offset:768 sc0 sc1\n\t"
            "global_load_dwordx4 %13, %16, off offset:832 sc0 sc1\n\t"
            "global_load_dwordx4 %14, %16, off offset:896 sc0 sc1\n\t"
            "global_load_dwordx4 %15, %16, off offset:960 sc0 sc1\n\t"
            "s_waitcnt vmcnt(0)"
            : "=&v"(a0),"=&v"(a1),"=&v"(a2),"=&v"(a3),
              "=&v"(a4),"=&v"(a5),"=&v"(a6),"=&v"(a7),
              "=&v"(a8),"=&v"(a9),"=&v"(a10),"=&v"(a11),
              "=&v"(a12),"=&v"(a13),"=&v"(a14),"=&v"(a15)
            : "v"(hq)
            : "memory");
        bf8_t af[16];
        af[0]=__builtin_bit_cast(bf8_t,a0);   af[1]=__builtin_bit_cast(bf8_t,a1);
        af[2]=__builtin_bit_cast(bf8_t,a2);   af[3]=__builtin_bit_cast(bf8_t,a3);
        af[4]=__builtin_bit_cast(bf8_t,a4);   af[5]=__builtin_bit_cast(bf8_t,a5);
        af[6]=__builtin_bit_cast(bf8_t,a6);   af[7]=__builtin_bit_cast(bf8_t,a7);
        af[8]=__builtin_bit_cast(bf8_t,a8);   af[9]=__builtin_bit_cast(bf8_t,a9);
        af[10]=__builtin_bit_cast(bf8_t,a10); af[11]=__builtin_bit_cast(bf8_t,a11);
        af[12]=__builtin_bit_cast(bf8_t,a12); af[13]=__builtin_bit_cast(bf8_t,a13);
        af[14]=__builtin_bit_cast(bf8_t,a14); af[15]=__builtin_bit_cast(bf8_t,a15);

        f32x4 aR = (f32x4){0.f,0.f,0.f,0.f};
        f32x4 aZ = (f32x4){0.f,0.f,0.f,0.f};
        f32x4 aN = (f32x4){0.f,0.f,0.f,0.f};
        #pragma unroll
        for (int kc = 0; kc < 16; kc++) {
            aR = __builtin_amdgcn_mfma_f32_16x16x32_bf16(af[kc], w[0][kc], aR, 0, 0, 0);
            aZ = __builtin_amdgcn_mfma_f32_16x16x32_bf16(af[kc], w[1][kc], aZ, 0, 0, 0);
            aN = __builtin_amdgcn_mfma_f32_16x16x32_bf16(af[kc], w[2][kc], aN, 0, 0, 0);
        }

        u16* hnb = hbfd + (long)((s + 1) & 1) * B * H;
        #pragma unroll
        for (int rg = 0; rg < 4; rg++) {
            int b = bg * 16 + q * 4 + rg;         // D layout: m = (lane>>4)*4+reg
            float r = sigm(xrv[rg] + aR[rg] + br);
            float z = sigm(xzv[rg] + aZ[rg] + bz);
            float n = tanhs(xnv[rg] + r * (aN[rg] + bn));
            float hh = (1.f - z) * n + z * hp[rg];
            hp[rg] = hh;
            u16 hv = f2b(hh);
            asm volatile("global_store_short %0, %1, off sc0 sc1"
                         :: "v"(hnb + (long)b * H + u), "v"((unsigned int)hv) : "memory");
            if (writeX1)
                x1out[((long)b * T + time) * 1024 + d * H + u] = hv;
        }

        // drain this wave's stores (WT ack => device-visible), then flag + poll.
        asm volatile("s_waitcnt vmcnt(0)" ::: "memory");
        if (sl < CT - 1) {
            int tgt = s + 1;
            if (lane == 0)
                asm volatile("global_store_dword %0, %1, off sc0 sc1"
                             :: "v"(myflag), "v"(tgt) : "memory");
            int v;
            do {
                asm volatile("global_load_dword %0, %1, off sc0 sc1\n\t"
                             "s_waitcnt vmcnt(0)"
                             : "=v"(v) : "v"(fpoll) : "memory");
            } while (!__all(v >= tgt));
        }
        // last step: no flag/poll — next dispatch is stream-ordered (kernel boundary).
    }

    // spill fp32 carry for next chunk dispatch / k_fc (kernel-boundary coherence)
    #pragma unroll
    for (int rg = 0; rg < 4; rg++)
        h32d[(long)(bg * 16 + q * 4 + rg) * H + u] = hp[rg];
}

// ------------------------------------------------------- final FC (fp32)
__global__ __launch_bounds__(256)
void k_fc(const float* __restrict__ h32, const float* __restrict__ fcw,
          const float* __restrict__ fcb, float* __restrict__ out) {
    int b   = blockIdx.x;
    int tid = threadIdx.x;
    float p[10];
    #pragma unroll
    for (int o = 0; o < 10; o++) p[o] = 0.f;
    for (int k = tid; k < 1024; k += 256) {
        int dd = k >> 9, kk = k & 511;
        float hv = h32[(long)dd * B * H + (long)b * H + kk];
        #pragma unroll
        for (int o = 0; o < 10; o++) p[o] += hv * fcw[o * 1024 + k];
    }
    __shared__ float red[10][256];
    #pragma unroll
    for (int o = 0; o < 10; o++) red[o][tid] = p[o];
    __syncthreads();
    for (int off = 128; off > 0; off >>= 1) {
        if (tid < off)
            #pragma unroll
            for (int o = 0; o < 10; o++) red[o][tid] += red[o][tid + off];
        __syncthreads();
    }
    if (tid < 10) out[b * 10 + tid] = red[tid][0] + fcb[tid];
}

// ------------------------------------------------------- launcher
extern "C" void kernel_launch(void* const* d_in, const int* in_sizes, int n_in,
                              void* d_out, int out_size, void* d_ws, size_t ws_size,
                              hipStream_t stream) {
    const int*   sent = (const int*)d_in[0];
    const float* emb  = (const float*)d_in[1];
    const float* wih0 = (const float*)d_in[2];
    const float* whh0 = (const float*)d_in[3];
    const float* bih0 = (const float*)d_in[4];
    const float* bhh0 = (const float*)d_in[5];
    const float* wih1 = (const float*)d_in[6];
    const float* whh1 = (const float*)d_in[7];
    const float* bih1 = (const float*)d_in[8];
    const float* bhh1 = (const float*)d_in[9];
    const float* fcw  = (const float*)d_in[10];
    const float* fcb  = (const float*)d_in[11];
    float* outp = (float*)d_out;

    // workspace layout — ~132.2 MB (proven-safe envelope: >=134.5 MB)
    char*  ws  = (char*)d_ws;
    float* xg  = (float*)(ws);                           // 2*CT*G3*B*4 = 50,331,648 B
    u16*   x1  = (u16*)(ws + 50331648L);                 // B*T*1024*2  = 67,108,864 B
    float* h32 = (float*)(ws + 50331648L + 67108864L);   // 2*B*H*4     =    262,144 B
    u16*   hbf = (u16*)(ws + 50331648L + 67108864L + 262144L);   // 262,144 B
    int*   bar = (int*)(ws + 50331648L + 67108864L + 262144L + 262144L); // 16,384 B flags
    u16*   wbf = (u16*)(ws + 50331648L + 67108864L + 262144L + 262144L + 16384L);
    u16* wih0b = wbf;                      // 2*1536*256  =   786,432 el
    u16* wih1b = wbf + 786432L;            // 2*1536*1024 = 3,145,728 el
    u16* whh0b = wbf + 786432L + 3145728L; // 2*1536*512  = 1,572,864 el
    u16* whh1b = whh0b + 1572864L;         // 1,572,864 el

    // convert weights fp32 -> bf16 (graph-safe, runs every launch)
    k_cvt<<<512, 256, 0, stream>>>(wih0, wih0b, 786432);
    k_cvt<<<512, 256, 0, stream>>>(wih1, wih1b, 3145728);
    k_cvt<<<512, 256, 0, stream>>>(whh0, whh0b, 1572864);
    k_cvt<<<512, 256, 0, stream>>>(whh1, whh1b, 1572864);

    dim3 gg(32, 12, 2);      // GEMM: 32 m-blocks x 12 n-tiles x 2 dirs
    dim3 gc(NUG, NBG, 2);    // recurrence: 32 unit-waves x 4 batch-groups x 2 dirs

    // ---- layer 0 (embedding gather fused into GEMM A-staging) ----
    k_init<<<512, 256, 0, stream>>>(h32, hbf, bar);
    for (int c = 0; c < T / CT; c++) {
        k_gemm_xg<<<gg, 256, 0, stream>>>(sent, emb, 1, wih0b, bih0, xg, E, c);
        k_chunk<<<gc, 64, 0, stream>>>(whh0b, bhh0, xg, h32, hbf, c, x1, 1, bar);
    }

    // ---- layer 1 (A = x1, already bf16) ----
    k_init<<<512, 256, 0, stream>>>(h32, hbf, bar);
    for (int c = 0; c < T / CT; c++) {
        k_gemm_xg<<<gg, 256, 0, stream>>>(sent, x1, 0, wih1b, bih1, xg, 2 * H, c);
        k_chunk<<<gc, 64, 0, stream>>>(whh1b, bhh1, xg, h32, hbf, c, (u16*)nullptr, 0, bar);
    }

    k_fc<<<B, 256, 0, stream>>>(h32, fcw, fcb, outp);
}

// Round 10
// 3350.932 us; speedup vs baseline: 1.6581x; 1.1317x over previous
//
#include <hip/hip_runtime.h>
#include <stdint.h>

#define H   512
#define B   64
#define T   512
#define E   256
#define G3  1536   // 3*H
#define CT  64     // time-chunk length (T/CT = 8 chunks)
#define NBG 4      // independent batch groups (16 batches each)
#define NUG 32     // unit blocks per direction (16 units each)

typedef short s16;
typedef unsigned short u16;
typedef unsigned int u32;
typedef __attribute__((ext_vector_type(8))) short   short8;
typedef __attribute__((ext_vector_type(4))) float   f32x4;
typedef __attribute__((ext_vector_type(4))) unsigned int u32x4;
typedef __attribute__((ext_vector_type(2))) unsigned int u32x2;
typedef __bf16 bf8_t __attribute__((ext_vector_type(8)));

__device__ __forceinline__ u16 f2b(float f) {
    union { float f; unsigned int i; } v; v.f = f;
    unsigned int r = v.i + 0x7FFF + ((v.i >> 16) & 1);
    return (u16)(r >> 16);
}
__device__ __forceinline__ float sigm(float x)  { return 1.f / (1.f + __expf(-x)); }
__device__ __forceinline__ float tanhs(float x) { return 1.f - 2.f / (1.f + __expf(2.f * x)); }

// ------------------------------------------------------- fp32 -> bf16 weight convert
__global__ void k_cvt(const float* __restrict__ src, u16* __restrict__ dst, int n) {
    int i = blockIdx.x * 256 + threadIdx.x;
    int stride = gridDim.x * 256;
    for (; i < n; i += stride) dst[i] = f2b(src[i]);
}

// ------------------------------------------------------- init h32/slots
__global__ void k_init(float* __restrict__ h32, u32* __restrict__ slots) {
    int i = blockIdx.x * 256 + threadIdx.x;      // 131072 u32 = 512 KB slot buffer
    slots[i] = 0;                                 // stamp 0 + h=0 (initial state h_0)
    if (i < 65536) h32[i] = 0.f;                 // 2 dirs * B*H fp32 carry
}

// ------------------------------------------------------- xg chunk GEMM (MFMA)
// Writes xgT[d][tl][n][b] (fp32) = A[b,t,:K] . Wbf[d][n][:K] + bih[d][n]
// m-mapping: b = m&63, tl = m>>6 (t = t0(d,c)+tl). MFMA operands are SWAPPED
// (first = B-rows) so D-cols carry m: the 16 store lanes (r16 -> b) write 16
// consecutive floats -> coalesced C stores. (Unchanged from round 7/9.)
#define BM 128
#define BN 128
#define BK 32

__global__ __launch_bounds__(256)
void k_gemm_xg(const int* __restrict__ sent, const void* __restrict__ Abuf, int aIsF32,
               const u16* __restrict__ Wbf, const float* __restrict__ bih,
               float* __restrict__ xgT, int K, int c) {
    int d  = blockIdx.z;
    int t0 = d ? (T - (c + 1) * CT) : c * CT;
    const u16* Bw = Wbf + (long)d * G3 * K;
    const float* bias = bih + (long)d * G3;
    float* C = xgT + (long)d * (long)CT * G3 * B;

    __shared__ __align__(16) s16 lA[BM * BK];
    __shared__ __align__(16) s16 lB[BN * BK];

    int tid  = threadIdx.x;
    int lane = tid & 63;
    int wv   = tid >> 6;
    int wm   = wv >> 1, wn = wv & 1;
    int q    = lane >> 4, r16 = lane & 15;

    long m0 = (long)blockIdx.x * BM;
    long n0 = (long)blockIdx.y * BN;

    const float* rowAf[2];
    const s16*   rowAh[2];
    const u16*   rowB[2];
    #pragma unroll
    for (int i = 0; i < 2; i++) {
        int ch = tid + i * 256;
        int r  = ch >> 2, cc = (ch & 3) * 8;
        long m = m0 + r;
        int  bb_ = (int)(m & 63), tl = (int)(m >> 6);   // m = (tl<<6)|b
        int  t  = t0 + tl;
        if (aIsF32) rowAf[i] = (const float*)Abuf + (long)sent[bb_ * T + t] * K + cc;
        else        rowAh[i] = (const s16*)Abuf + ((long)bb_ * T + t) * K + cc;
        rowB[i] = Bw + (n0 + r) * K + cc;
    }

    f32x4 acc[4][4];
    #pragma unroll
    for (int i = 0; i < 4; i++)
        #pragma unroll
        for (int j = 0; j < 4; j++) acc[i][j] = (f32x4){0.f, 0.f, 0.f, 0.f};

    for (long k0 = 0; k0 < K; k0 += BK) {
        #pragma unroll
        for (int i = 0; i < 2; i++) {
            if (aIsF32) {
                float4 v0 = *(const float4*)(rowAf[i] + k0);
                float4 v1 = *(const float4*)(rowAf[i] + k0 + 4);
                short8 pk;
                pk[0] = (s16)f2b(v0.x); pk[1] = (s16)f2b(v0.y);
                pk[2] = (s16)f2b(v0.z); pk[3] = (s16)f2b(v0.w);
                pk[4] = (s16)f2b(v1.x); pk[5] = (s16)f2b(v1.y);
                pk[6] = (s16)f2b(v1.z); pk[7] = (s16)f2b(v1.w);
                ((short8*)lA)[tid + i * 256] = pk;
            } else {
                ((short8*)lA)[tid + i * 256] = *(const short8*)(rowAh[i] + k0);
            }
            ((short8*)lB)[tid + i * 256] = *(const short8*)((const s16*)rowB[i] + k0);
        }
        __syncthreads();

        bf8_t af[4], bf[4];
        #pragma unroll
        for (int mt = 0; mt < 4; mt++)
            af[mt] = ((const bf8_t*)lA)[(wm * 64 + mt * 16 + r16) * 4 + q];
        #pragma unroll
        for (int nt = 0; nt < 4; nt++)
            bf[nt] = ((const bf8_t*)lB)[(wn * 64 + nt * 16 + r16) * 4 + q];
        #pragma unroll
        for (int mt = 0; mt < 4; mt++)
            #pragma unroll
            for (int nt = 0; nt < 4; nt++)
                acc[mt][nt] = __builtin_amdgcn_mfma_f32_16x16x32_bf16(
                                  bf[nt], af[mt], acc[mt][nt], 0, 0, 0);   // swapped
        __syncthreads();
    }

    // D layout (swapped): row (q*4+rg) -> n-sub, col (r16) -> m-sub
    #pragma unroll
    for (int nt = 0; nt < 4; nt++) {
        f32x4 bv = *(const f32x4*)(bias + n0 + wn * 64 + nt * 16 + q * 4);
        #pragma unroll
        for (int mt = 0; mt < 4; mt++) {
            long m = m0 + wm * 64 + mt * 16 + r16;
            long tl = m >> 6, b = m & 63;
            #pragma unroll
            for (int rg = 0; rg < 4; rg++) {
                long n = n0 + wn * 64 + nt * 16 + q * 4 + rg;
                C[(tl * G3 + n) * B + b] = acc[mt][nt][rg] + bv[rg];
            }
        }
    }
}

// ------------------------------------------------------- wave-autonomous chunk recurrence
// Grid (NUG=32, NBG=4, 2 dirs) x 64 thr: 256 single-wave blocks, all co-resident.
// SWAPPED recurrence MFMA: A := Whh (register frags — identical bytes to R9's
// B-frags; compiler remats to cached loads), B := h frags. D gives lane (q,cc)
// the pre-acts for batch bg*16+cc at units u0+q*4..+3 -> producer emits its h
// as ONE 16B self-certifying slot {h01,stamp,h23,stamp}. NO drain, NO flag
// (saves one device-scope RT/step vs R9 — measured R5 vs R8: -0.58us/step).
// Consumer: cheap PROBE (one 16B load/lane sampling all 32 producers) then
// monolithic BULK (32 x dwordx4, each instr 1024B lane-contiguous) + FULL
// stamp verify, straggler -> retry (R5-proven loop). Parity-2 slot buffers;
// max producer/consumer skew = 1 step on opposite parity (R2/R3/R5 argument).
// Slot block per (d,parity,bg) = 32 KB: slot (j = u/4, b_local) at byte
// ((j>>3)*2 + (j&1))*1024 + ((j>>1)&3)*256 + b_local*16.
__global__ __launch_bounds__(64, 1)
void k_chunk(const u16* __restrict__ Whhbf, const float* __restrict__ bhh,
             const float* __restrict__ xgT, float* __restrict__ h32,
             u32* __restrict__ slots, int c, u16* __restrict__ x1out, int writeX1) {
    int ug = blockIdx.x;                 // unit group: units ug*16..+15
    int bg = blockIdx.y;                 // batch group: batches bg*16..+15
    int d  = blockIdx.z;
    int lane = threadIdx.x;              // 0..63
    int q = lane >> 4, cc = lane & 15;
    int u0 = ug * 16;
    int bgl = bg * 16 + cc;              // this lane's batch (D-col side)

    const u16* W    = Whhbf + (long)d * G3 * H;
    const float* bb = bhh + (long)d * G3;
    const float* xgf = xgT + (long)d * (long)CT * G3 * B;
    float* h32d = h32 + (long)d * B * H;
    char* slotbase = (char*)slots;

    // ---- weight slice as registers (A-frag; same bytes as R9's B-frag) ----
    bf8_t w[3][16];
    #pragma unroll
    for (int gate = 0; gate < 3; gate++)
        #pragma unroll
        for (int kc = 0; kc < 16; kc++)
            w[gate][kc] = *(const bf8_t*)(W + (long)(gate * H + u0 + cc) * H + kc * 32 + q * 8);

    // per-unit biases, f32x4 over rg (units u0+q*4..+3)
    f32x4 brv = *(const f32x4*)(bb + u0 + q * 4);
    f32x4 bzv = *(const f32x4*)(bb + H + u0 + q * 4);
    f32x4 bnv = *(const f32x4*)(bb + 2 * H + u0 + q * 4);

    // fp32 h-carry: lane holds h[b=bgl][u0+q*4+rg] -> f32x4
    f32x4 hp = *(const f32x4*)(h32d + (long)bgl * H + u0 + q * 4);

    // producer slot byte offset (within a 32KB (d,parity,bg) block)
    int jw = ug * 4 + q;                 // unit quad index of this lane's 4 units
    long off_wr = (long)((jw >> 3) * 2 + (jw & 1)) * 1024
                + (long)((jw >> 1) & 3) * 256 + cc * 16;
    // probe sample: j = 2*lane covers all 32 producer waves (ug = lane>>1)
    int jp = lane * 2;
    long off_prb = (long)((jp >> 3) * 2 + (jp & 1)) * 1024
                 + (long)((jp >> 1) & 3) * 256 + (lane & 15) * 16;

    int base = c * CT;

    for (int sl = 0; sl < CT; sl++) {
        int s    = base + sl;
        int tl   = d ? (CT - 1 - sl) : sl;
        int time = d ? (T - 1 - s) : s;
        int tgt  = s;
        u32 st1  = (u32)(s + 1);

        // xg loads: lane needs xg[tl][u0+q*4+jj][bgl], jj=0..3, x3 gates.
        // 12 cached scalar loads (each instr: 4x64B segments) — issued first,
        // latency hidden under probe/bulk RT.
        const float* xgb = xgf + ((long)tl * G3 + u0 + q * 4) * B + bgl;
        float xr[4], xz[4], xn[4];
        #pragma unroll
        for (int jj = 0; jj < 4; jj++) {
            xr[jj] = xgb[(long)jj * B];
            xz[jj] = xgb[(long)H * B + (long)jj * B];
            xn[jj] = xgb[(long)2 * H * B + (long)jj * B];
        }

        const char* domb = slotbase + (long)(((d * 2 + (s & 1)) * 4 + bg) * 32768);
        const char* prb = domb + off_prb;
        const char* pb  = domb + lane * 16;
        const char* qa0 = pb;
        const char* qa1 = pb + 4096;
        const char* qa2 = pb + 8192;
        const char* qa3 = pb + 12288;
        const char* qa4 = pb + 16384;
        const char* qa5 = pb + 20480;
        const char* qa6 = pb + 24576;
        const char* qa7 = pb + 28672;
        u32x4 p0,p1,p2,p3,p4,p5,p6,p7,p8,p9,p10,p11,p12,p13,p14,p15;
        u32x4 p16,p17,p18,p19,p20,p21,p22,p23,p24,p25,p26,p27,p28,p29,p30,p31;

        for (;;) {
            // ---- phase 1: cheap probe (1 KB/wave/iter, samples every producer) ----
            for (;;) {
                u32x4 pr;
                asm volatile("global_load_dwordx4 %0, %1, off sc0 sc1\n\t"
                             "s_waitcnt vmcnt(0)"
                             : "=&v"(pr) : "v"(prb) : "memory");
                __builtin_amdgcn_sched_barrier(0);
                int pm = min((int)pr[1], (int)pr[3]);
                if (__all(pm >= tgt)) break;
            }
            // ---- phase 2: bulk load (once) + full verify ----
            asm volatile(
                "global_load_dwordx4 %0,  %16, off sc0 sc1\n\t"
                "global_load_dwordx4 %1,  %16, off offset:1024 sc0 sc1\n\t"
                "global_load_dwordx4 %2,  %16, off offset:2048 sc0 sc1\n\t"
                "global_load_dwordx4 %3,  %16, off offset:3072 sc0 sc1\n\t"
                "global_load_dwordx4 %4,  %17, off sc0 sc1\n\t"
                "global_load_dwordx4 %5,  %17, off offset:1024 sc0 sc1\n\t"
                "global_load_dwordx4 %6,  %17, off offset:2048 sc0 sc1\n\t"
                "global_load_dwordx4 %7,  %17, off offset:3072 sc0 sc1\n\t"
                "global_load_dwordx4 %8,  %18, off sc0 sc1\n\t"
                "global_load_dwordx4 %9,  %18, off offset:1024 sc0 sc1\n\t"
                "global_load_dwordx4 %10, %18, off offset:2048 sc0 sc1\n\t"
                "global_load_dwordx4 %11, %18, off offset:3072 sc0 sc1\n\t"
                "global_load_dwordx4 %12, %19, off sc0 sc1\n\t"
                "global_load_dwordx4 %13, %19, off offset:1024 sc0 sc1\n\t"
                "global_load_dwordx4 %14, %19, off offset:2048 sc0 sc1\n\t"
                "global_load_dwordx4 %15, %19, off offset:3072 sc0 sc1"
                : "=&v"(p0),"=&v"(p1),"=&v"(p2),"=&v"(p3),
                  "=&v"(p4),"=&v"(p5),"=&v"(p6),"=&v"(p7),
                  "=&v"(p8),"=&v"(p9),"=&v"(p10),"=&v"(p11),
                  "=&v"(p12),"=&v"(p13),"=&v"(p14),"=&v"(p15)
                : "v"(qa0), "v"(qa1), "v"(qa2), "v"(qa3)
                : "memory");
            asm volatile(
                "global_load_dwordx4 %0,  %16, off sc0 sc1\n\t"
                "global_load_dwordx4 %1,  %16, off offset:1024 sc0 sc1\n\t"
                "global_load_dwordx4 %2,  %16, off offset:2048 sc0 sc1\n\t"
                "global_load_dwordx4 %3,  %16, off offset:3072 sc0 sc1\n\t"
                "global_load_dwordx4 %4,  %17, off sc0 sc1\n\t"
                "global_load_dwordx4 %5,  %17, off offset:1024 sc0 sc1\n\t"
                "global_load_dwordx4 %6,  %17, off offset:2048 sc0 sc1\n\t"
                "global_load_dwordx4 %7,  %17, off offset:3072 sc0 sc1\n\t"
                "global_load_dwordx4 %8,  %18, off sc0 sc1\n\t"
                "global_load_dwordx4 %9,  %18, off offset:1024 sc0 sc1\n\t"
                "global_load_dwordx4 %10, %18, off offset:2048 sc0 sc1\n\t"
                "global_load_dwordx4 %11, %18, off offset:3072 sc0 sc1\n\t"
                "global_load_dwordx4 %12, %19, off sc0 sc1\n\t"
                "global_load_dwordx4 %13, %19, off offset:1024 sc0 sc1\n\t"
                "global_load_dwordx4 %14, %19, off offset:2048 sc0 sc1\n\t"
                "global_load_dwordx4 %15, %19, off offset:3072 sc0 sc1\n\t"
                "s_waitcnt vmcnt(0)"
                : "=&v"(p16),"=&v"(p17),"=&v"(p18),"=&v"(p19),
                  "=&v"(p20),"=&v"(p21),"=&v"(p22),"=&v"(p23),
                  "=&v"(p24),"=&v"(p25),"=&v"(p26),"=&v"(p27),
                  "=&v"(p28),"=&v"(p29),"=&v"(p30),"=&v"(p31)
                : "v"(qa4), "v"(qa5), "v"(qa6), "v"(qa7)
                : "memory");
            __builtin_amdgcn_sched_barrier(0);   // stamp checks must not hoist above vmcnt
            int mn = min((int)p0[1], (int)p0[3]);
            #define MN2(x) mn = min(mn, min((int)x[1], (int)x[3]));
            MN2(p1)  MN2(p2)  MN2(p3)  MN2(p4)  MN2(p5)  MN2(p6)  MN2(p7)
            MN2(p8)  MN2(p9)  MN2(p10) MN2(p11) MN2(p12) MN2(p13) MN2(p14) MN2(p15)
            MN2(p16) MN2(p17) MN2(p18) MN2(p19) MN2(p20) MN2(p21) MN2(p22) MN2(p23)
            MN2(p24) MN2(p25) MN2(p26) MN2(p27) MN2(p28) MN2(p29) MN2(p30) MN2(p31)
            #undef MN2
            if (__all(mn >= tgt)) break;
        }

        // ---- MFMA (swapped): A = W regs, B = h frags from slot pairs ----
        f32x4 aR = (f32x4){0.f,0.f,0.f,0.f};
        f32x4 aZ = (f32x4){0.f,0.f,0.f,0.f};
        f32x4 aN = (f32x4){0.f,0.f,0.f,0.f};
        #define STEP_KC(kc, A_, B_) { \
            u32x4 fw = (u32x4){A_[0], A_[2], B_[0], B_[2]}; \
            bf8_t hb = __builtin_bit_cast(bf8_t, fw); \
            aR = __builtin_amdgcn_mfma_f32_16x16x32_bf16(w[0][kc], hb, aR, 0, 0, 0); \
            aZ = __builtin_amdgcn_mfma_f32_16x16x32_bf16(w[1][kc], hb, aZ, 0, 0, 0); \
            aN = __builtin_amdgcn_mfma_f32_16x16x32_bf16(w[2][kc], hb, aN, 0, 0, 0); }
        STEP_KC(0,  p0,  p1)  STEP_KC(1,  p2,  p3)  STEP_KC(2,  p4,  p5)  STEP_KC(3,  p6,  p7)
        STEP_KC(4,  p8,  p9)  STEP_KC(5,  p10, p11) STEP_KC(6,  p12, p13) STEP_KC(7,  p14, p15)
        STEP_KC(8,  p16, p17) STEP_KC(9,  p18, p19) STEP_KC(10, p20, p21) STEP_KC(11, p22, p23)
        STEP_KC(12, p24, p25) STEP_KC(13, p26, p27) STEP_KC(14, p28, p29) STEP_KC(15, p30, p31)
        #undef STEP_KC

        // ---- gates: lane (q,cc) -> batch bgl, units u0+q*4+rg ----
        float hh[4];
        #pragma unroll
        for (int rg = 0; rg < 4; rg++) {
            float r = sigm(xr[rg] + aR[rg] + brv[rg]);
            float z = sigm(xz[rg] + aZ[rg] + bzv[rg]);
            float n = tanhs(xn[rg] + r * (aN[rg] + bnv[rg]));
            hh[rg] = (1.f - z) * n + z * hp[rg];
        }
        hp = (f32x4){hh[0], hh[1], hh[2], hh[3]};

        // ---- single 16B self-certifying slot store (parity (s+1)&1, stamp s+1) ----
        u32 w0 = (u32)f2b(hh[0]) | ((u32)f2b(hh[1]) << 16);
        u32 w1 = (u32)f2b(hh[2]) | ((u32)f2b(hh[3]) << 16);
        u32x4 sv = (u32x4){w0, st1, w1, st1};
        char* ps = slotbase + (long)(((d * 2 + ((s + 1) & 1)) * 4 + bg) * 32768) + off_wr;
        asm volatile("global_store_dwordx4 %0, %1, off sc0 sc1"
                     :: "v"(ps), "v"(sv) : "memory");

        if (writeX1) {
            u32x2 xv = (u32x2){w0, w1};   // 4 consecutive units at batch bgl
            *(u32x2*)(x1out + ((long)bgl * T + time) * 1024 + d * H + u0 + q * 4) = xv;
        }
        // NO drain, NO flag: next step's probe/verify certifies visibility.
    }

    // spill fp32 carry for next chunk dispatch / k_fc (kernel-boundary coherence)
    *(f32x4*)(h32d + (long)bgl * H + u0 + q * 4) = hp;
}

// ------------------------------------------------------- final FC (fp32)
__global__ __launch_bounds__(256)
void k_fc(const float* __restrict__ h32, const float* __restrict__ fcw,
          const float* __restrict__ fcb, float* __restrict__ out) {
    int b   = blockIdx.x;
    int tid = threadIdx.x;
    float p[10];
    #pragma unroll
    for (int o = 0; o < 10; o++) p[o] = 0.f;
    for (int k = tid; k < 1024; k += 256) {
        int dd = k >> 9, kk = k & 511;
        float hv = h32[(long)dd * B * H + (long)b * H + kk];
        #pragma unroll
        for (int o = 0; o < 10; o++) p[o] += hv * fcw[o * 1024 + k];
    }
    __shared__ float red[10][256];
    #pragma unroll
    for (int o = 0; o < 10; o++) red[o][tid] = p[o];
    __syncthreads();
    for (int off = 128; off > 0; off >>= 1) {
        if (tid < off)
            #pragma unroll
            for (int o = 0; o < 10; o++) red[o][tid] += red[o][tid + off];
        __syncthreads();
    }
    if (tid < 10) out[b * 10 + tid] = red[tid][0] + fcb[tid];
}

// ------------------------------------------------------- launcher
extern "C" void kernel_launch(void* const* d_in, const int* in_sizes, int n_in,
                              void* d_out, int out_size, void* d_ws, size_t ws_size,
                              hipStream_t stream) {
    const int*   sent = (const int*)d_in[0];
    const float* emb  = (const float*)d_in[1];
    const float* wih0 = (const float*)d_in[2];
    const float* whh0 = (const float*)d_in[3];
    const float* bih0 = (const float*)d_in[4];
    const float* bhh0 = (const float*)d_in[5];
    const float* wih1 = (const float*)d_in[6];
    const float* whh1 = (const float*)d_in[7];
    const float* bih1 = (const float*)d_in[8];
    const float* bhh1 = (const float*)d_in[9];
    const float* fcw  = (const float*)d_in[10];
    const float* fcb  = (const float*)d_in[11];
    float* outp = (float*)d_out;

    // workspace layout — ~132.4 MB (proven-safe envelope: >=134.5 MB)
    char*  ws  = (char*)d_ws;
    float* xg  = (float*)(ws);                           // 2*CT*G3*B*4 = 50,331,648 B
    u16*   x1  = (u16*)(ws + 50331648L);                 // B*T*1024*2  = 67,108,864 B
    float* h32 = (float*)(ws + 50331648L + 67108864L);   // 2*B*H*4     =    262,144 B
    u32*   slt = (u32*)(ws + 50331648L + 67108864L + 262144L);   // slots 524,288 B
    u16*   wbf = (u16*)(ws + 50331648L + 67108864L + 262144L + 524288L);
    u16* wih0b = wbf;                      // 2*1536*256  =   786,432 el
    u16* wih1b = wbf + 786432L;            // 2*1536*1024 = 3,145,728 el
    u16* whh0b = wbf + 786432L + 3145728L; // 2*1536*512  = 1,572,864 el
    u16* whh1b = whh0b + 1572864L;         // 1,572,864 el

    // convert weights fp32 -> bf16 (graph-safe, runs every launch)
    k_cvt<<<512, 256, 0, stream>>>(wih0, wih0b, 786432);
    k_cvt<<<512, 256, 0, stream>>>(wih1, wih1b, 3145728);
    k_cvt<<<512, 256, 0, stream>>>(whh0, whh0b, 1572864);
    k_cvt<<<512, 256, 0, stream>>>(whh1, whh1b, 1572864);

    dim3 gg(32, 12, 2);      // GEMM: 32 m-blocks x 12 n-tiles x 2 dirs
    dim3 gc(NUG, NBG, 2);    // recurrence: 32 unit-waves x 4 batch-groups x 2 dirs

    // ---- layer 0 (embedding gather fused into GEMM A-staging) ----
    k_init<<<512, 256, 0, stream>>>(h32, slt);
    for (int c = 0; c < T / CT; c++) {
        k_gemm_xg<<<gg, 256, 0, stream>>>(sent, emb, 1, wih0b, bih0, xg, E, c);
        k_chunk<<<gc, 64, 0, stream>>>(whh0b, bhh0, xg, h32, slt, c, x1, 1);
    }

    // ---- layer 1 (A = x1, already bf16) ----
    k_init<<<512, 256, 0, stream>>>(h32, slt);
    for (int c = 0; c < T / CT; c++) {
        k_gemm_xg<<<gg, 256, 0, stream>>>(sent, x1, 0, wih1b, bih1, xg, 2 * H, c);
        k_chunk<<<gc, 64, 0, stream>>>(whh1b, bhh1, xg, h32, slt, c, (u16*)nullptr, 0);
    }

    k_fc<<<B, 256, 0, stream>>>(h32, fcw, fcb, outp);
}

// Round 11
// 3313.538 us; speedup vs baseline: 1.6768x; 1.0113x over previous
//
#include <hip/hip_runtime.h>
#include <stdint.h>

#define H   512
#define B   64
#define T   512
#define E   256
#define G3  1536   // 3*H
#define CT  64     // time-chunk length (T/CT = 8 chunks)
#define NBG 4      // independent batch groups (16 batches each)
#define NUG 32     // unit blocks per direction (16 units each)

typedef short s16;
typedef unsigned short u16;
typedef unsigned int u32;
typedef __attribute__((ext_vector_type(8))) short   short8;
typedef __attribute__((ext_vector_type(4))) float   f32x4;
typedef __attribute__((ext_vector_type(4))) unsigned int u32x4;
typedef __attribute__((ext_vector_type(2))) unsigned int u32x2;
typedef __bf16 bf8_t __attribute__((ext_vector_type(8)));

__device__ __forceinline__ u16 f2b(float f) {
    union { float f; unsigned int i; } v; v.f = f;
    unsigned int r = v.i + 0x7FFF + ((v.i >> 16) & 1);
    return (u16)(r >> 16);
}
__device__ __forceinline__ float sigm(float x)  { return 1.f / (1.f + __expf(-x)); }
__device__ __forceinline__ float tanhs(float x) { return 1.f - 2.f / (1.f + __expf(2.f * x)); }

// ------------------------------------------------------- fp32 -> bf16 weight convert
__global__ void k_cvt(const float* __restrict__ src, u16* __restrict__ dst, int n) {
    int i = blockIdx.x * 256 + threadIdx.x;
    int stride = gridDim.x * 256;
    for (; i < n; i += stride) dst[i] = f2b(src[i]);
}

// ------------------------------------------------------- init h32/slots
__global__ void k_init(float* __restrict__ h32, u32* __restrict__ slots) {
    int i = blockIdx.x * 256 + threadIdx.x;      // 131072 u32 = 512 KB slot buffer
    slots[i] = 0;                                 // stamp 0 + h=0 (initial state h_0)
    if (i < 65536) h32[i] = 0.f;                 // 2 dirs * B*H fp32 carry
}

// ------------------------------------------------------- xg chunk GEMM (MFMA)
// Writes xgT[d][tl][n][b] (fp32) = A[b,t,:K] . Wbf[d][n][:K] + bih[d][n]
// m-mapping: b = m&63, tl = m>>6 (t = t0(d,c)+tl). MFMA operands are SWAPPED
// (first = B-rows) so D-cols carry m: the 16 store lanes (r16 -> b) write 16
// consecutive floats -> coalesced C stores. (Unchanged from round 7/9/10.)
#define BM 128
#define BN 128
#define BK 32

__global__ __launch_bounds__(256)
void k_gemm_xg(const int* __restrict__ sent, const void* __restrict__ Abuf, int aIsF32,
               const u16* __restrict__ Wbf, const float* __restrict__ bih,
               float* __restrict__ xgT, int K, int c) {
    int d  = blockIdx.z;
    int t0 = d ? (T - (c + 1) * CT) : c * CT;
    const u16* Bw = Wbf + (long)d * G3 * K;
    const float* bias = bih + (long)d * G3;
    float* C = xgT + (long)d * (long)CT * G3 * B;

    __shared__ __align__(16) s16 lA[BM * BK];
    __shared__ __align__(16) s16 lB[BN * BK];

    int tid  = threadIdx.x;
    int lane = tid & 63;
    int wv   = tid >> 6;
    int wm   = wv >> 1, wn = wv & 1;
    int q    = lane >> 4, r16 = lane & 15;

    long m0 = (long)blockIdx.x * BM;
    long n0 = (long)blockIdx.y * BN;

    const float* rowAf[2];
    const s16*   rowAh[2];
    const u16*   rowB[2];
    #pragma unroll
    for (int i = 0; i < 2; i++) {
        int ch = tid + i * 256;
        int r  = ch >> 2, cc = (ch & 3) * 8;
        long m = m0 + r;
        int  bb_ = (int)(m & 63), tl = (int)(m >> 6);   // m = (tl<<6)|b
        int  t  = t0 + tl;
        if (aIsF32) rowAf[i] = (const float*)Abuf + (long)sent[bb_ * T + t] * K + cc;
        else        rowAh[i] = (const s16*)Abuf + ((long)bb_ * T + t) * K + cc;
        rowB[i] = Bw + (n0 + r) * K + cc;
    }

    f32x4 acc[4][4];
    #pragma unroll
    for (int i = 0; i < 4; i++)
        #pragma unroll
        for (int j = 0; j < 4; j++) acc[i][j] = (f32x4){0.f, 0.f, 0.f, 0.f};

    for (long k0 = 0; k0 < K; k0 += BK) {
        #pragma unroll
        for (int i = 0; i < 2; i++) {
            if (aIsF32) {
                float4 v0 = *(const float4*)(rowAf[i] + k0);
                float4 v1 = *(const float4*)(rowAf[i] + k0 + 4);
                short8 pk;
                pk[0] = (s16)f2b(v0.x); pk[1] = (s16)f2b(v0.y);
                pk[2] = (s16)f2b(v0.z); pk[3] = (s16)f2b(v0.w);
                pk[4] = (s16)f2b(v1.x); pk[5] = (s16)f2b(v1.y);
                pk[6] = (s16)f2b(v1.z); pk[7] = (s16)f2b(v1.w);
                ((short8*)lA)[tid + i * 256] = pk;
            } else {
                ((short8*)lA)[tid + i * 256] = *(const short8*)(rowAh[i] + k0);
            }
            ((short8*)lB)[tid + i * 256] = *(const short8*)((const s16*)rowB[i] + k0);
        }
        __syncthreads();

        bf8_t af[4], bf[4];
        #pragma unroll
        for (int mt = 0; mt < 4; mt++)
            af[mt] = ((const bf8_t*)lA)[(wm * 64 + mt * 16 + r16) * 4 + q];
        #pragma unroll
        for (int nt = 0; nt < 4; nt++)
            bf[nt] = ((const bf8_t*)lB)[(wn * 64 + nt * 16 + r16) * 4 + q];
        #pragma unroll
        for (int mt = 0; mt < 4; mt++)
            #pragma unroll
            for (int nt = 0; nt < 4; nt++)
                acc[mt][nt] = __builtin_amdgcn_mfma_f32_16x16x32_bf16(
                                  bf[nt], af[mt], acc[mt][nt], 0, 0, 0);   // swapped
        __syncthreads();
    }

    // D layout (swapped): row (q*4+rg) -> n-sub, col (r16) -> m-sub
    #pragma unroll
    for (int nt = 0; nt < 4; nt++) {
        f32x4 bv = *(const f32x4*)(bias + n0 + wn * 64 + nt * 16 + q * 4);
        #pragma unroll
        for (int mt = 0; mt < 4; mt++) {
            long m = m0 + wm * 64 + mt * 16 + r16;
            long tl = m >> 6, b = m & 63;
            #pragma unroll
            for (int rg = 0; rg < 4; rg++) {
                long n = n0 + wn * 64 + nt * 16 + q * 4 + rg;
                C[(tl * G3 + n) * B + b] = acc[mt][nt][rg] + bv[rg];
            }
        }
    }
}

// ------------------------------------------------------- wave-autonomous chunk recurrence
// Grid (NUG=32, NBG=4, 2 dirs) x 64 thr: 256 single-wave blocks, all co-resident.
// SWAPPED recurrence MFMA: A := Whh (register frags; compiler remats to cached
// loads), B := h frags. Producer emits its h as ONE 16B self-certifying slot
// {h01,stamp,h23,stamp}. NO drain, NO flag, NO probe: consumer = FUSED bulk
// verify-retry (R3/R5-proven loop) — issue the 32-load bulk, vmcnt(0), verify
// ALL stamps, retry on straggler. Merges discovery and data fetch into one RT:
// step chain = store visibility + bulk (2 RTs) vs probe+bulk's ~3 (R10 evidence:
// fused 4.11 < probe 4.49 us/step at NUG=16). Parity-2 slot buffers; max
// producer/consumer skew = 1 step on opposite parity. Deadlock-free: every wave
// stores unconditionally before waiting; stamps monotonic.
// Slot block per (d,parity,bg) = 32 KB: slot (j = u/4, b_local) at byte
// ((j>>3)*2 + (j&1))*1024 + ((j>>1)&3)*256 + b_local*16; every bulk instr
// reads 1024 lane-contiguous bytes.
__global__ __launch_bounds__(64, 1)
void k_chunk(const u16* __restrict__ Whhbf, const float* __restrict__ bhh,
             const float* __restrict__ xgT, float* __restrict__ h32,
             u32* __restrict__ slots, int c, u16* __restrict__ x1out, int writeX1) {
    int ug = blockIdx.x;                 // unit group: units ug*16..+15
    int bg = blockIdx.y;                 // batch group: batches bg*16..+15
    int d  = blockIdx.z;
    int lane = threadIdx.x;              // 0..63
    int q = lane >> 4, cc = lane & 15;
    int u0 = ug * 16;
    int bgl = bg * 16 + cc;              // this lane's batch (D-col side)

    const u16* W    = Whhbf + (long)d * G3 * H;
    const float* bb = bhh + (long)d * G3;
    const float* xgf = xgT + (long)d * (long)CT * G3 * B;
    float* h32d = h32 + (long)d * B * H;
    char* slotbase = (char*)slots;

    // ---- weight slice as registers (A-frag; compiler remats to cached loads) ----
    bf8_t w[3][16];
    #pragma unroll
    for (int gate = 0; gate < 3; gate++)
        #pragma unroll
        for (int kc = 0; kc < 16; kc++)
            w[gate][kc] = *(const bf8_t*)(W + (long)(gate * H + u0 + cc) * H + kc * 32 + q * 8);

    // per-unit biases, f32x4 over rg (units u0+q*4..+3)
    f32x4 brv = *(const f32x4*)(bb + u0 + q * 4);
    f32x4 bzv = *(const f32x4*)(bb + H + u0 + q * 4);
    f32x4 bnv = *(const f32x4*)(bb + 2 * H + u0 + q * 4);

    // fp32 h-carry: lane holds h[b=bgl][u0+q*4+rg] -> f32x4
    f32x4 hp = *(const f32x4*)(h32d + (long)bgl * H + u0 + q * 4);

    // producer slot byte offset (within a 32KB (d,parity,bg) block)
    int jw = ug * 4 + q;                 // unit quad index of this lane's 4 units
    long off_wr = (long)((jw >> 3) * 2 + (jw & 1)) * 1024
                + (long)((jw >> 1) & 3) * 256 + cc * 16;

    int base = c * CT;

    for (int sl = 0; sl < CT; sl++) {
        int s    = base + sl;
        int tl   = d ? (CT - 1 - sl) : sl;
        int time = d ? (T - 1 - s) : s;
        int tgt  = s;
        u32 st1  = (u32)(s + 1);

        // xg loads: lane needs xg[tl][u0+q*4+jj][bgl], jj=0..3, x3 gates.
        // Issued first; latency hidden under the bulk RT.
        const float* xgb = xgf + ((long)tl * G3 + u0 + q * 4) * B + bgl;
        float xr[4], xz[4], xn[4];
        #pragma unroll
        for (int jj = 0; jj < 4; jj++) {
            xr[jj] = xgb[(long)jj * B];
            xz[jj] = xgb[(long)H * B + (long)jj * B];
            xn[jj] = xgb[(long)2 * H * B + (long)jj * B];
        }

        const char* domb = slotbase + (long)(((d * 2 + (s & 1)) * 4 + bg) * 32768);
        const char* pb  = domb + lane * 16;
        const char* qa0 = pb;
        const char* qa1 = pb + 4096;
        const char* qa2 = pb + 8192;
        const char* qa3 = pb + 12288;
        const char* qa4 = pb + 16384;
        const char* qa5 = pb + 20480;
        const char* qa6 = pb + 24576;
        const char* qa7 = pb + 28672;
        u32x4 p0,p1,p2,p3,p4,p5,p6,p7,p8,p9,p10,p11,p12,p13,p14,p15;
        u32x4 p16,p17,p18,p19,p20,p21,p22,p23,p24,p25,p26,p27,p28,p29,p30,p31;

        for (;;) {
            // ---- fused bulk load + full stamp verify (retry on straggler) ----
            asm volatile(
                "global_load_dwordx4 %0,  %16, off sc0 sc1\n\t"
                "global_load_dwordx4 %1,  %16, off offset:1024 sc0 sc1\n\t"
                "global_load_dwordx4 %2,  %16, off offset:2048 sc0 sc1\n\t"
                "global_load_dwordx4 %3,  %16, off offset:3072 sc0 sc1\n\t"
                "global_load_dwordx4 %4,  %17, off sc0 sc1\n\t"
                "global_load_dwordx4 %5,  %17, off offset:1024 sc0 sc1\n\t"
                "global_load_dwordx4 %6,  %17, off offset:2048 sc0 sc1\n\t"
                "global_load_dwordx4 %7,  %17, off offset:3072 sc0 sc1\n\t"
                "global_load_dwordx4 %8,  %18, off sc0 sc1\n\t"
                "global_load_dwordx4 %9,  %18, off offset:1024 sc0 sc1\n\t"
                "global_load_dwordx4 %10, %18, off offset:2048 sc0 sc1\n\t"
                "global_load_dwordx4 %11, %18, off offset:3072 sc0 sc1\n\t"
                "global_load_dwordx4 %12, %19, off sc0 sc1\n\t"
                "global_load_dwordx4 %13, %19, off offset:1024 sc0 sc1\n\t"
                "global_load_dwordx4 %14, %19, off offset:2048 sc0 sc1\n\t"
                "global_load_dwordx4 %15, %19, off offset:3072 sc0 sc1"
                : "=&v"(p0),"=&v"(p1),"=&v"(p2),"=&v"(p3),
                  "=&v"(p4),"=&v"(p5),"=&v"(p6),"=&v"(p7),
                  "=&v"(p8),"=&v"(p9),"=&v"(p10),"=&v"(p11),
                  "=&v"(p12),"=&v"(p13),"=&v"(p14),"=&v"(p15)
                : "v"(qa0), "v"(qa1), "v"(qa2), "v"(qa3)
                : "memory");
            asm volatile(
                "global_load_dwordx4 %0,  %16, off sc0 sc1\n\t"
                "global_load_dwordx4 %1,  %16, off offset:1024 sc0 sc1\n\t"
                "global_load_dwordx4 %2,  %16, off offset:2048 sc0 sc1\n\t"
                "global_load_dwordx4 %3,  %16, off offset:3072 sc0 sc1\n\t"
                "global_load_dwordx4 %4,  %17, off sc0 sc1\n\t"
                "global_load_dwordx4 %5,  %17, off offset:1024 sc0 sc1\n\t"
                "global_load_dwordx4 %6,  %17, off offset:2048 sc0 sc1\n\t"
                "global_load_dwordx4 %7,  %17, off offset:3072 sc0 sc1\n\t"
                "global_load_dwordx4 %8,  %18, off sc0 sc1\n\t"
                "global_load_dwordx4 %9,  %18, off offset:1024 sc0 sc1\n\t"
                "global_load_dwordx4 %10, %18, off offset:2048 sc0 sc1\n\t"
                "global_load_dwordx4 %11, %18, off offset:3072 sc0 sc1\n\t"
                "global_load_dwordx4 %12, %19, off sc0 sc1\n\t"
                "global_load_dwordx4 %13, %19, off offset:1024 sc0 sc1\n\t"
                "global_load_dwordx4 %14, %19, off offset:2048 sc0 sc1\n\t"
                "global_load_dwordx4 %15, %19, off offset:3072 sc0 sc1\n\t"
                "s_waitcnt vmcnt(0)"
                : "=&v"(p16),"=&v"(p17),"=&v"(p18),"=&v"(p19),
                  "=&v"(p20),"=&v"(p21),"=&v"(p22),"=&v"(p23),
                  "=&v"(p24),"=&v"(p25),"=&v"(p26),"=&v"(p27),
                  "=&v"(p28),"=&v"(p29),"=&v"(p30),"=&v"(p31)
                : "v"(qa4), "v"(qa5), "v"(qa6), "v"(qa7)
                : "memory");
            __builtin_amdgcn_sched_barrier(0);   // stamp checks must not hoist above vmcnt
            int mn = min((int)p0[1], (int)p0[3]);
            #define MN2(x) mn = min(mn, min((int)x[1], (int)x[3]));
            MN2(p1)  MN2(p2)  MN2(p3)  MN2(p4)  MN2(p5)  MN2(p6)  MN2(p7)
            MN2(p8)  MN2(p9)  MN2(p10) MN2(p11) MN2(p12) MN2(p13) MN2(p14) MN2(p15)
            MN2(p16) MN2(p17) MN2(p18) MN2(p19) MN2(p20) MN2(p21) MN2(p22) MN2(p23)
            MN2(p24) MN2(p25) MN2(p26) MN2(p27) MN2(p28) MN2(p29) MN2(p30) MN2(p31)
            #undef MN2
            if (__all(mn >= tgt)) break;
        }

        // ---- MFMA (swapped): A = W regs, B = h frags from slot pairs ----
        f32x4 aR = (f32x4){0.f,0.f,0.f,0.f};
        f32x4 aZ = (f32x4){0.f,0.f,0.f,0.f};
        f32x4 aN = (f32x4){0.f,0.f,0.f,0.f};
        #define STEP_KC(kc, A_, B_) { \
            u32x4 fw = (u32x4){A_[0], A_[2], B_[0], B_[2]}; \
            bf8_t hb = __builtin_bit_cast(bf8_t, fw); \
            aR = __builtin_amdgcn_mfma_f32_16x16x32_bf16(w[0][kc], hb, aR, 0, 0, 0); \
            aZ = __builtin_amdgcn_mfma_f32_16x16x32_bf16(w[1][kc], hb, aZ, 0, 0, 0); \
            aN = __builtin_amdgcn_mfma_f32_16x16x32_bf16(w[2][kc], hb, aN, 0, 0, 0); }
        STEP_KC(0,  p0,  p1)  STEP_KC(1,  p2,  p3)  STEP_KC(2,  p4,  p5)  STEP_KC(3,  p6,  p7)
        STEP_KC(4,  p8,  p9)  STEP_KC(5,  p10, p11) STEP_KC(6,  p12, p13) STEP_KC(7,  p14, p15)
        STEP_KC(8,  p16, p17) STEP_KC(9,  p18, p19) STEP_KC(10, p20, p21) STEP_KC(11, p22, p23)
        STEP_KC(12, p24, p25) STEP_KC(13, p26, p27) STEP_KC(14, p28, p29) STEP_KC(15, p30, p31)
        #undef STEP_KC

        // ---- gates: lane (q,cc) -> batch bgl, units u0+q*4+rg ----
        float hh[4];
        #pragma unroll
        for (int rg = 0; rg < 4; rg++) {
            float r = sigm(xr[rg] + aR[rg] + brv[rg]);
            float z = sigm(xz[rg] + aZ[rg] + bzv[rg]);
            float n = tanhs(xn[rg] + r * (aN[rg] + bnv[rg]));
            hh[rg] = (1.f - z) * n + z * hp[rg];
        }
        hp = (f32x4){hh[0], hh[1], hh[2], hh[3]};

        // ---- single 16B self-certifying slot store (parity (s+1)&1, stamp s+1) ----
        u32 w0 = (u32)f2b(hh[0]) | ((u32)f2b(hh[1]) << 16);
        u32 w1 = (u32)f2b(hh[2]) | ((u32)f2b(hh[3]) << 16);
        u32x4 sv = (u32x4){w0, st1, w1, st1};
        char* ps = slotbase + (long)(((d * 2 + ((s + 1) & 1)) * 4 + bg) * 32768) + off_wr;
        asm volatile("global_store_dwordx4 %0, %1, off sc0 sc1"
                     :: "v"(ps), "v"(sv) : "memory");

        if (writeX1) {
            u32x2 xv = (u32x2){w0, w1};   // 4 consecutive units at batch bgl
            *(u32x2*)(x1out + ((long)bgl * T + time) * 1024 + d * H + u0 + q * 4) = xv;
        }
        // NO drain, NO flag, NO probe: next step's bulk verify certifies visibility.
    }

    // spill fp32 carry for next chunk dispatch / k_fc (kernel-boundary coherence)
    *(f32x4*)(h32d + (long)bgl * H + u0 + q * 4) = hp;
}

// ------------------------------------------------------- final FC (fp32)
__global__ __launch_bounds__(256)
void k_fc(const float* __restrict__ h32, const float* __restrict__ fcw,
          const float* __restrict__ fcb, float* __restrict__ out) {
    int b   = blockIdx.x;
    int tid = threadIdx.x;
    float p[10];
    #pragma unroll
    for (int o = 0; o < 10; o++) p[o] = 0.f;
    for (int k = tid; k < 1024; k += 256) {
        int dd = k >> 9, kk = k & 511;
        float hv = h32[(long)dd * B * H + (long)b * H + kk];
        #pragma unroll
        for (int o = 0; o < 10; o++) p[o] += hv * fcw[o * 1024 + k];
    }
    __shared__ float red[10][256];
    #pragma unroll
    for (int o = 0; o < 10; o++) red[o][tid] = p[o];
    __syncthreads();
    for (int off = 128; off > 0; off >>= 1) {
        if (tid < off)
            #pragma unroll
            for (int o = 0; o < 10; o++) red[o][tid] += red[o][tid + off];
        __syncthreads();
    }
    if (tid < 10) out[b * 10 + tid] = red[tid][0] + fcb[tid];
}

// ------------------------------------------------------- launcher
extern "C" void kernel_launch(void* const* d_in, const int* in_sizes, int n_in,
                              void* d_out, int out_size, void* d_ws, size_t ws_size,
                              hipStream_t stream) {
    const int*   sent = (const int*)d_in[0];
    const float* emb  = (const float*)d_in[1];
    const float* wih0 = (const float*)d_in[2];
    const float* whh0 = (const float*)d_in[3];
    const float* bih0 = (const float*)d_in[4];
    const float* bhh0 = (const float*)d_in[5];
    const float* wih1 = (const float*)d_in[6];
    const float* whh1 = (const float*)d_in[7];
    const float* bih1 = (const float*)d_in[8];
    const float* bhh1 = (const float*)d_in[9];
    const float* fcw  = (const float*)d_in[10];
    const float* fcb  = (const float*)d_in[11];
    float* outp = (float*)d_out;

    // workspace layout — ~132.4 MB (proven-safe envelope: >=134.5 MB)
    char*  ws  = (char*)d_ws;
    float* xg  = (float*)(ws);                           // 2*CT*G3*B*4 = 50,331,648 B
    u16*   x1  = (u16*)(ws + 50331648L);                 // B*T*1024*2  = 67,108,864 B
    float* h32 = (float*)(ws + 50331648L + 67108864L);   // 2*B*H*4     =    262,144 B
    u32*   slt = (u32*)(ws + 50331648L + 67108864L + 262144L);   // slots 524,288 B
    u16*   wbf = (u16*)(ws + 50331648L + 67108864L + 262144L + 524288L);
    u16* wih0b = wbf;                      // 2*1536*256  =   786,432 el
    u16* wih1b = wbf + 786432L;            // 2*1536*1024 = 3,145,728 el
    u16* whh0b = wbf + 786432L + 3145728L; // 2*1536*512  = 1,572,864 el
    u16* whh1b = whh0b + 1572864L;         // 1,572,864 el

    // convert weights fp32 -> bf16 (graph-safe, runs every launch)
    k_cvt<<<512, 256, 0, stream>>>(wih0, wih0b, 786432);
    k_cvt<<<512, 256, 0, stream>>>(wih1, wih1b, 3145728);
    k_cvt<<<512, 256, 0, stream>>>(whh0, whh0b, 1572864);
    k_cvt<<<512, 256, 0, stream>>>(whh1, whh1b, 1572864);

    dim3 gg(32, 12, 2);      // GEMM: 32 m-blocks x 12 n-tiles x 2 dirs
    dim3 gc(NUG, NBG, 2);    // recurrence: 32 unit-waves x 4 batch-groups x 2 dirs

    // ---- layer 0 (embedding gather fused into GEMM A-staging) ----
    k_init<<<512, 256, 0, stream>>>(h32, slt);
    for (int c = 0; c < T / CT; c++) {
        k_gemm_xg<<<gg, 256, 0, stream>>>(sent, emb, 1, wih0b, bih0, xg, E, c);
        k_chunk<<<gc, 64, 0, stream>>>(whh0b, bhh0, xg, h32, slt, c, x1, 1);
    }

    // ---- layer 1 (A = x1, already bf16) ----
    k_init<<<512, 256, 0, stream>>>(h32, slt);
    for (int c = 0; c < T / CT; c++) {
        k_gemm_xg<<<gg, 256, 0, stream>>>(sent, x1, 0, wih1b, bih1, xg, 2 * H, c);
        k_chunk<<<gc, 64, 0, stream>>>(whh1b, bhh1, xg, h32, slt, c, (u16*)nullptr, 0);
    }

    k_fc<<<B, 256, 0, stream>>>(h32, fcw, fcb, outp);
}

// Round 12
// 3072.231 us; speedup vs baseline: 1.8085x; 1.0785x over previous
//
#include <hip/hip_runtime.h>
#include <stdint.h>

#define H   512
#define B   64
#define T   512
#define E   256
#define G3  1536   // 3*H
#define CT  64     // time-chunk length (T/CT = 8 chunks)
#define NBG 4      // independent batch groups (16 batches each)
#define NUG 32     // unit blocks per direction (16 units each)

typedef short s16;
typedef unsigned short u16;
typedef unsigned int u32;
typedef __attribute__((ext_vector_type(8))) short   short8;
typedef __attribute__((ext_vector_type(4))) float   f32x4;
typedef __attribute__((ext_vector_type(4))) unsigned int u32x4;
typedef __attribute__((ext_vector_type(2))) unsigned int u32x2;
typedef __bf16 bf8_t __attribute__((ext_vector_type(8)));

__device__ __forceinline__ u16 f2b(float f) {
    union { float f; unsigned int i; } v; v.f = f;
    unsigned int r = v.i + 0x7FFF + ((v.i >> 16) & 1);
    return (u16)(r >> 16);
}
__device__ __forceinline__ float sigm(float x)  { return 1.f / (1.f + __expf(-x)); }
__device__ __forceinline__ float tanhs(float x) { return 1.f - 2.f / (1.f + __expf(2.f * x)); }

// ------------------------------------------------------- fp32 -> bf16 weight convert
__global__ void k_cvt(const float* __restrict__ src, u16* __restrict__ dst, int n) {
    int i = blockIdx.x * 256 + threadIdx.x;
    int stride = gridDim.x * 256;
    for (; i < n; i += stride) dst[i] = f2b(src[i]);
}

// ------------------------------------------------------- init h32/slots
__global__ void k_init(float* __restrict__ h32, u32* __restrict__ slots) {
    int i = blockIdx.x * 256 + threadIdx.x;      // 131072 u32 = 512 KB slot buffer
    slots[i] = 0;                                 // stamp 0 + h=0 (initial state h_0)
    if (i < 65536) h32[i] = 0.f;                 // 2 dirs * B*H fp32 carry
}

// ------------------------------------------------------- xg chunk GEMM (MFMA)
// Writes xgT[d][tl][n][b] (fp32) = A[b,t,:K] . Wbf[d][n][:K] + bih[d][n]
// m-mapping: b = m&63, tl = m>>6 (t = t0(d,c)+tl). MFMA operands are SWAPPED
// (first = B-rows) so D-cols carry m: the 16 store lanes (r16 -> b) write 16
// consecutive floats -> coalesced C stores. (Unchanged from round 7/9/10/11.)
#define BM 128
#define BN 128
#define BK 32

__global__ __launch_bounds__(256)
void k_gemm_xg(const int* __restrict__ sent, const void* __restrict__ Abuf, int aIsF32,
               const u16* __restrict__ Wbf, const float* __restrict__ bih,
               float* __restrict__ xgT, int K, int c) {
    int d  = blockIdx.z;
    int t0 = d ? (T - (c + 1) * CT) : c * CT;
    const u16* Bw = Wbf + (long)d * G3 * K;
    const float* bias = bih + (long)d * G3;
    float* C = xgT + (long)d * (long)CT * G3 * B;

    __shared__ __align__(16) s16 lA[BM * BK];
    __shared__ __align__(16) s16 lB[BN * BK];

    int tid  = threadIdx.x;
    int lane = tid & 63;
    int wv   = tid >> 6;
    int wm   = wv >> 1, wn = wv & 1;
    int q    = lane >> 4, r16 = lane & 15;

    long m0 = (long)blockIdx.x * BM;
    long n0 = (long)blockIdx.y * BN;

    const float* rowAf[2];
    const s16*   rowAh[2];
    const u16*   rowB[2];
    #pragma unroll
    for (int i = 0; i < 2; i++) {
        int ch = tid + i * 256;
        int r  = ch >> 2, cc = (ch & 3) * 8;
        long m = m0 + r;
        int  bb_ = (int)(m & 63), tl = (int)(m >> 6);   // m = (tl<<6)|b
        int  t  = t0 + tl;
        if (aIsF32) rowAf[i] = (const float*)Abuf + (long)sent[bb_ * T + t] * K + cc;
        else        rowAh[i] = (const s16*)Abuf + ((long)bb_ * T + t) * K + cc;
        rowB[i] = Bw + (n0 + r) * K + cc;
    }

    f32x4 acc[4][4];
    #pragma unroll
    for (int i = 0; i < 4; i++)
        #pragma unroll
        for (int j = 0; j < 4; j++) acc[i][j] = (f32x4){0.f, 0.f, 0.f, 0.f};

    for (long k0 = 0; k0 < K; k0 += BK) {
        #pragma unroll
        for (int i = 0; i < 2; i++) {
            if (aIsF32) {
                float4 v0 = *(const float4*)(rowAf[i] + k0);
                float4 v1 = *(const float4*)(rowAf[i] + k0 + 4);
                short8 pk;
                pk[0] = (s16)f2b(v0.x); pk[1] = (s16)f2b(v0.y);
                pk[2] = (s16)f2b(v0.z); pk[3] = (s16)f2b(v0.w);
                pk[4] = (s16)f2b(v1.x); pk[5] = (s16)f2b(v1.y);
                pk[6] = (s16)f2b(v1.z); pk[7] = (s16)f2b(v1.w);
                ((short8*)lA)[tid + i * 256] = pk;
            } else {
                ((short8*)lA)[tid + i * 256] = *(const short8*)(rowAh[i] + k0);
            }
            ((short8*)lB)[tid + i * 256] = *(const short8*)((const s16*)rowB[i] + k0);
        }
        __syncthreads();

        bf8_t af[4], bf[4];
        #pragma unroll
        for (int mt = 0; mt < 4; mt++)
            af[mt] = ((const bf8_t*)lA)[(wm * 64 + mt * 16 + r16) * 4 + q];
        #pragma unroll
        for (int nt = 0; nt < 4; nt++)
            bf[nt] = ((const bf8_t*)lB)[(wn * 64 + nt * 16 + r16) * 4 + q];
        #pragma unroll
        for (int mt = 0; mt < 4; mt++)
            #pragma unroll
            for (int nt = 0; nt < 4; nt++)
                acc[mt][nt] = __builtin_amdgcn_mfma_f32_16x16x32_bf16(
                                  bf[nt], af[mt], acc[mt][nt], 0, 0, 0);   // swapped
        __syncthreads();
    }

    // D layout (swapped): row (q*4+rg) -> n-sub, col (r16) -> m-sub
    #pragma unroll
    for (int nt = 0; nt < 4; nt++) {
        f32x4 bv = *(const f32x4*)(bias + n0 + wn * 64 + nt * 16 + q * 4);
        #pragma unroll
        for (int mt = 0; mt < 4; mt++) {
            long m = m0 + wm * 64 + mt * 16 + r16;
            long tl = m >> 6, b = m & 63;
            #pragma unroll
            for (int rg = 0; rg < 4; rg++) {
                long n = n0 + wn * 64 + nt * 16 + q * 4 + rg;
                C[(tl * G3 + n) * B + b] = acc[mt][nt][rg] + bv[rg];
            }
        }
    }
}

// bulk load macro: 32 x dwordx4, each instr 1024 lane-contiguous bytes, scope SC
#define BULK(SC) \
    asm volatile( \
        "global_load_dwordx4 %0,  %16, off " SC "\n\t" \
        "global_load_dwordx4 %1,  %16, off offset:1024 " SC "\n\t" \
        "global_load_dwordx4 %2,  %16, off offset:2048 " SC "\n\t" \
        "global_load_dwordx4 %3,  %16, off offset:3072 " SC "\n\t" \
        "global_load_dwordx4 %4,  %17, off " SC "\n\t" \
        "global_load_dwordx4 %5,  %17, off offset:1024 " SC "\n\t" \
        "global_load_dwordx4 %6,  %17, off offset:2048 " SC "\n\t" \
        "global_load_dwordx4 %7,  %17, off offset:3072 " SC "\n\t" \
        "global_load_dwordx4 %8,  %18, off " SC "\n\t" \
        "global_load_dwordx4 %9,  %18, off offset:1024 " SC "\n\t" \
        "global_load_dwordx4 %10, %18, off offset:2048 " SC "\n\t" \
        "global_load_dwordx4 %11, %18, off offset:3072 " SC "\n\t" \
        "global_load_dwordx4 %12, %19, off " SC "\n\t" \
        "global_load_dwordx4 %13, %19, off offset:1024 " SC "\n\t" \
        "global_load_dwordx4 %14, %19, off offset:2048 " SC "\n\t" \
        "global_load_dwordx4 %15, %19, off offset:3072 " SC \
        : "=&v"(p0),"=&v"(p1),"=&v"(p2),"=&v"(p3), \
          "=&v"(p4),"=&v"(p5),"=&v"(p6),"=&v"(p7), \
          "=&v"(p8),"=&v"(p9),"=&v"(p10),"=&v"(p11), \
          "=&v"(p12),"=&v"(p13),"=&v"(p14),"=&v"(p15) \
        : "v"(qa0), "v"(qa1), "v"(qa2), "v"(qa3) \
        : "memory"); \
    asm volatile( \
        "global_load_dwordx4 %0,  %16, off " SC "\n\t" \
        "global_load_dwordx4 %1,  %16, off offset:1024 " SC "\n\t" \
        "global_load_dwordx4 %2,  %16, off offset:2048 " SC "\n\t" \
        "global_load_dwordx4 %3,  %16, off offset:3072 " SC "\n\t" \
        "global_load_dwordx4 %4,  %17, off " SC "\n\t" \
        "global_load_dwordx4 %5,  %17, off offset:1024 " SC "\n\t" \
        "global_load_dwordx4 %6,  %17, off offset:2048 " SC "\n\t" \
        "global_load_dwordx4 %7,  %17, off offset:3072 " SC "\n\t" \
        "global_load_dwordx4 %8,  %18, off " SC "\n\t" \
        "global_load_dwordx4 %9,  %18, off offset:1024 " SC "\n\t" \
        "global_load_dwordx4 %10, %18, off offset:2048 " SC "\n\t" \
        "global_load_dwordx4 %11, %18, off offset:3072 " SC "\n\t" \
        "global_load_dwordx4 %12, %19, off " SC "\n\t" \
        "global_load_dwordx4 %13, %19, off offset:1024 " SC "\n\t" \
        "global_load_dwordx4 %14, %19, off offset:2048 " SC "\n\t" \
        "global_load_dwordx4 %15, %19, off offset:3072 " SC "\n\t" \
        "s_waitcnt vmcnt(0)" \
        : "=&v"(p16),"=&v"(p17),"=&v"(p18),"=&v"(p19), \
          "=&v"(p20),"=&v"(p21),"=&v"(p22),"=&v"(p23), \
          "=&v"(p24),"=&v"(p25),"=&v"(p26),"=&v"(p27), \
          "=&v"(p28),"=&v"(p29),"=&v"(p30),"=&v"(p31) \
        : "v"(qa4), "v"(qa5), "v"(qa6), "v"(qa7) \
        : "memory");

// ------------------------------------------------------- wave-autonomous chunk recurrence
// 1-D grid of 256 single-wave blocks: dom = bid&7 -> (d,bg); ug = bid>>3.
// Under round-robin block->XCD placement each domain's 32 waves share ONE XCD,
// so slot traffic can stay in that XCD's L2. FAIL-SAFE locality (no decision
// logic, no hang vector):
//  - producers DUAL-STORE each slot: sc0 (fast, local L2) then sc0 sc1
//    (durable, MALL) — identical bytes, fire-and-forget.
//  - consumers start with sc0 bulk reads; the dual-stamp verify rejects any
//    stale/partial data (stale line => stale stamp => fail). After 8 fails in
//    a step the wave STICKILY escalates to sc0 sc1 reads = exactly R11's
//    proven path reading the durable copy. Worst case == R11 + a few us.
// Slot layout/verify/retry semantics unchanged from R11.
__global__ __launch_bounds__(64, 1)
void k_chunk(const u16* __restrict__ Whhbf, const float* __restrict__ bhh,
             const float* __restrict__ xgT, float* __restrict__ h32,
             u32* __restrict__ slots, int c, u16* __restrict__ x1out, int writeX1) {
    int bid = blockIdx.x;
    int dom = bid & 7;                   // sync domain: one XCD under round-robin
    int ug  = bid >> 3;                  // unit group: units ug*16..+15
    int d   = dom >> 2;
    int bg  = dom & 3;
    int lane = threadIdx.x;              // 0..63
    int q = lane >> 4, cc = lane & 15;
    int u0 = ug * 16;
    int bgl = bg * 16 + cc;              // this lane's batch (D-col side)

    const u16* W    = Whhbf + (long)d * G3 * H;
    const float* bb = bhh + (long)d * G3;
    const float* xgf = xgT + (long)d * (long)CT * G3 * B;
    float* h32d = h32 + (long)d * B * H;
    char* slotbase = (char*)slots;

    // ---- weight slice as registers (A-frag; compiler remats to cached loads) ----
    bf8_t w[3][16];
    #pragma unroll
    for (int gate = 0; gate < 3; gate++)
        #pragma unroll
        for (int kc = 0; kc < 16; kc++)
            w[gate][kc] = *(const bf8_t*)(W + (long)(gate * H + u0 + cc) * H + kc * 32 + q * 8);

    // per-unit biases, f32x4 over rg (units u0+q*4..+3)
    f32x4 brv = *(const f32x4*)(bb + u0 + q * 4);
    f32x4 bzv = *(const f32x4*)(bb + H + u0 + q * 4);
    f32x4 bnv = *(const f32x4*)(bb + 2 * H + u0 + q * 4);

    // fp32 h-carry: lane holds h[b=bgl][u0+q*4+rg] -> f32x4
    f32x4 hp = *(const f32x4*)(h32d + (long)bgl * H + u0 + q * 4);

    // producer slot byte offset (within a 32KB (d,parity,bg) block)
    int jw = ug * 4 + q;                 // unit quad index of this lane's 4 units
    long off_wr = (long)((jw >> 3) * 2 + (jw & 1)) * 1024
                + (long)((jw >> 1) & 3) * 256 + cc * 16;

    int base = c * CT;
    bool fast = true;                    // sticky: escalate to sc1 reads on trouble

    for (int sl = 0; sl < CT; sl++) {
        int s    = base + sl;
        int tl   = d ? (CT - 1 - sl) : sl;
        int time = d ? (T - 1 - s) : s;
        int tgt  = s;
        u32 st1  = (u32)(s + 1);

        // xg loads: issued first; latency hidden under the bulk RT.
        const float* xgb = xgf + ((long)tl * G3 + u0 + q * 4) * B + bgl;
        float xr[4], xz[4], xn[4];
        #pragma unroll
        for (int jj = 0; jj < 4; jj++) {
            xr[jj] = xgb[(long)jj * B];
            xz[jj] = xgb[(long)H * B + (long)jj * B];
            xn[jj] = xgb[(long)2 * H * B + (long)jj * B];
        }

        const char* domb = slotbase + (long)(((d * 2 + (s & 1)) * 4 + bg) * 32768);
        const char* pb  = domb + lane * 16;
        const char* qa0 = pb;
        const char* qa1 = pb + 4096;
        const char* qa2 = pb + 8192;
        const char* qa3 = pb + 12288;
        const char* qa4 = pb + 16384;
        const char* qa5 = pb + 20480;
        const char* qa6 = pb + 24576;
        const char* qa7 = pb + 28672;
        u32x4 p0,p1,p2,p3,p4,p5,p6,p7,p8,p9,p10,p11,p12,p13,p14,p15;
        u32x4 p16,p17,p18,p19,p20,p21,p22,p23,p24,p25,p26,p27,p28,p29,p30,p31;

        int fails = 0;
        for (;;) {
            // ---- fused bulk load + full stamp verify (retry on straggler) ----
            if (fast) { BULK("sc0") }
            else      { BULK("sc0 sc1") }
            __builtin_amdgcn_sched_barrier(0);   // stamp checks must not hoist above vmcnt
            int mn = min((int)p0[1], (int)p0[3]);
            #define MN2(x) mn = min(mn, min((int)x[1], (int)x[3]));
            MN2(p1)  MN2(p2)  MN2(p3)  MN2(p4)  MN2(p5)  MN2(p6)  MN2(p7)
            MN2(p8)  MN2(p9)  MN2(p10) MN2(p11) MN2(p12) MN2(p13) MN2(p14) MN2(p15)
            MN2(p16) MN2(p17) MN2(p18) MN2(p19) MN2(p20) MN2(p21) MN2(p22) MN2(p23)
            MN2(p24) MN2(p25) MN2(p26) MN2(p27) MN2(p28) MN2(p29) MN2(p30) MN2(p31)
            #undef MN2
            if (__all(mn >= tgt)) break;
            if (++fails > 8) fast = false;   // sticky escalation to durable path
        }

        // ---- MFMA (swapped): A = W regs, B = h frags from slot pairs ----
        f32x4 aR = (f32x4){0.f,0.f,0.f,0.f};
        f32x4 aZ = (f32x4){0.f,0.f,0.f,0.f};
        f32x4 aN = (f32x4){0.f,0.f,0.f,0.f};
        #define STEP_KC(kc, A_, B_) { \
            u32x4 fw = (u32x4){A_[0], A_[2], B_[0], B_[2]}; \
            bf8_t hb = __builtin_bit_cast(bf8_t, fw); \
            aR = __builtin_amdgcn_mfma_f32_16x16x32_bf16(w[0][kc], hb, aR, 0, 0, 0); \
            aZ = __builtin_amdgcn_mfma_f32_16x16x32_bf16(w[1][kc], hb, aZ, 0, 0, 0); \
            aN = __builtin_amdgcn_mfma_f32_16x16x32_bf16(w[2][kc], hb, aN, 0, 0, 0); }
        STEP_KC(0,  p0,  p1)  STEP_KC(1,  p2,  p3)  STEP_KC(2,  p4,  p5)  STEP_KC(3,  p6,  p7)
        STEP_KC(4,  p8,  p9)  STEP_KC(5,  p10, p11) STEP_KC(6,  p12, p13) STEP_KC(7,  p14, p15)
        STEP_KC(8,  p16, p17) STEP_KC(9,  p18, p19) STEP_KC(10, p20, p21) STEP_KC(11, p22, p23)
        STEP_KC(12, p24, p25) STEP_KC(13, p26, p27) STEP_KC(14, p28, p29) STEP_KC(15, p30, p31)
        #undef STEP_KC

        // ---- gates: lane (q,cc) -> batch bgl, units u0+q*4+rg ----
        float hh[4];
        #pragma unroll
        for (int rg = 0; rg < 4; rg++) {
            float r = sigm(xr[rg] + aR[rg] + brv[rg]);
            float z = sigm(xz[rg] + aZ[rg] + bzv[rg]);
            float n = tanhs(xn[rg] + r * (aN[rg] + bnv[rg]));
            hh[rg] = (1.f - z) * n + z * hp[rg];
        }
        hp = (f32x4){hh[0], hh[1], hh[2], hh[3]};

        // ---- dual-store self-certifying slot (parity (s+1)&1, stamp s+1) ----
        u32 w0 = (u32)f2b(hh[0]) | ((u32)f2b(hh[1]) << 16);
        u32 w1 = (u32)f2b(hh[2]) | ((u32)f2b(hh[3]) << 16);
        u32x4 sv = (u32x4){w0, st1, w1, st1};
        char* ps = slotbase + (long)(((d * 2 + ((s + 1) & 1)) * 4 + bg) * 32768) + off_wr;
        asm volatile("global_store_dwordx4 %0, %1, off sc0"
                     :: "v"(ps), "v"(sv) : "memory");        // fast copy (local L2)
        asm volatile("global_store_dwordx4 %0, %1, off sc0 sc1"
                     :: "v"(ps), "v"(sv) : "memory");        // durable copy (MALL)

        if (writeX1) {
            u32x2 xv = (u32x2){w0, w1};   // 4 consecutive units at batch bgl
            *(u32x2*)(x1out + ((long)bgl * T + time) * 1024 + d * H + u0 + q * 4) = xv;
        }
        // NO drain, NO flag: next step's bulk verify certifies visibility.
    }

    // spill fp32 carry for next chunk dispatch / k_fc (kernel-boundary coherence)
    *(f32x4*)(h32d + (long)bgl * H + u0 + q * 4) = hp;
}
#undef BULK

// ------------------------------------------------------- final FC (fp32)
__global__ __launch_bounds__(256)
void k_fc(const float* __restrict__ h32, const float* __restrict__ fcw,
          const float* __restrict__ fcb, float* __restrict__ out) {
    int b   = blockIdx.x;
    int tid = threadIdx.x;
    float p[10];
    #pragma unroll
    for (int o = 0; o < 10; o++) p[o] = 0.f;
    for (int k = tid; k < 1024; k += 256) {
        int dd = k >> 9, kk = k & 511;
        float hv = h32[(long)dd * B * H + (long)b * H + kk];
        #pragma unroll
        for (int o = 0; o < 10; o++) p[o] += hv * fcw[o * 1024 + k];
    }
    __shared__ float red[10][256];
    #pragma unroll
    for (int o = 0; o < 10; o++) red[o][tid] = p[o];
    __syncthreads();
    for (int off = 128; off > 0; off >>= 1) {
        if (tid < off)
            #pragma unroll
            for (int o = 0; o < 10; o++) red[o][tid] += red[o][tid + off];
        __syncthreads();
    }
    if (tid < 10) out[b * 10 + tid] = red[tid][0] + fcb[tid];
}

// ------------------------------------------------------- launcher
extern "C" void kernel_launch(void* const* d_in, const int* in_sizes, int n_in,
                              void* d_out, int out_size, void* d_ws, size_t ws_size,
                              hipStream_t stream) {
    const int*   sent = (const int*)d_in[0];
    const float* emb  = (const float*)d_in[1];
    const float* wih0 = (const float*)d_in[2];
    const float* whh0 = (const float*)d_in[3];
    const float* bih0 = (const float*)d_in[4];
    const float* bhh0 = (const float*)d_in[5];
    const float* wih1 = (const float*)d_in[6];
    const float* whh1 = (const float*)d_in[7];
    const float* bih1 = (const float*)d_in[8];
    const float* bhh1 = (const float*)d_in[9];
    const float* fcw  = (const float*)d_in[10];
    const float* fcb  = (const float*)d_in[11];
    float* outp = (float*)d_out;

    // workspace layout — ~132.4 MB (proven-safe envelope: >=134.5 MB)
    char*  ws  = (char*)d_ws;
    float* xg  = (float*)(ws);                           // 2*CT*G3*B*4 = 50,331,648 B
    u16*   x1  = (u16*)(ws + 50331648L);                 // B*T*1024*2  = 67,108,864 B
    float* h32 = (float*)(ws + 50331648L + 67108864L);   // 2*B*H*4     =    262,144 B
    u32*   slt = (u32*)(ws + 50331648L + 67108864L + 262144L);   // slots 524,288 B
    u16*   wbf = (u16*)(ws + 50331648L + 67108864L + 262144L + 524288L);
    u16* wih0b = wbf;                      // 2*1536*256  =   786,432 el
    u16* wih1b = wbf + 786432L;            // 2*1536*1024 = 3,145,728 el
    u16* whh0b = wbf + 786432L + 3145728L; // 2*1536*512  = 1,572,864 el
    u16* whh1b = whh0b + 1572864L;         // 1,572,864 el

    // convert weights fp32 -> bf16 (graph-safe, runs every launch)
    k_cvt<<<512, 256, 0, stream>>>(wih0, wih0b, 786432);
    k_cvt<<<512, 256, 0, stream>>>(wih1, wih1b, 3145728);
    k_cvt<<<512, 256, 0, stream>>>(whh0, whh0b, 1572864);
    k_cvt<<<512, 256, 0, stream>>>(whh1, whh1b, 1572864);

    dim3 gg(32, 12, 2);      // GEMM: 32 m-blocks x 12 n-tiles x 2 dirs
    // recurrence: 1-D grid of 256 so dom = bid&7 groups each domain on one XCD

    // ---- layer 0 (embedding gather fused into GEMM A-staging) ----
    k_init<<<512, 256, 0, stream>>>(h32, slt);
    for (int c = 0; c < T / CT; c++) {
        k_gemm_xg<<<gg, 256, 0, stream>>>(sent, emb, 1, wih0b, bih0, xg, E, c);
        k_chunk<<<256, 64, 0, stream>>>(whh0b, bhh0, xg, h32, slt, c, x1, 1);
    }

    // ---- layer 1 (A = x1, already bf16) ----
    k_init<<<512, 256, 0, stream>>>(h32, slt);
    for (int c = 0; c < T / CT; c++) {
        k_gemm_xg<<<gg, 256, 0, stream>>>(sent, x1, 0, wih1b, bih1, xg, 2 * H, c);
        k_chunk<<<256, 64, 0, stream>>>(whh1b, bhh1, xg, h32, slt, c, (u16*)nullptr, 0);
    }

    k_fc<<<B, 256, 0, stream>>>(h32, fcw, fcb, outp);
}